// Round 23
// baseline (208.532 us; speedup 1.0000x reference)
//
#include <hip/hip_runtime.h>
#include <math.h>

#define BB 2
#define SS 2048
#define EE 1024
#define HH 16
#define LL 5
#define DH 64
#define QS (3 * 1024)  // QKV fused row stride

typedef __attribute__((ext_vector_type(8))) short bf16x8;
typedef __attribute__((ext_vector_type(4))) float f32x4;

__device__ __forceinline__ unsigned short f2bf(float f) {
  unsigned u = __float_as_uint(f);
  u += 0x7fffu + ((u >> 16) & 1u);
  return (unsigned short)(u >> 16);
}
__device__ __forceinline__ float bf2f(unsigned short u) {
  return __uint_as_float((unsigned)u << 16);
}
__device__ __forceinline__ f32x4 mfma16(bf16x8 a, bf16x8 b, f32x4 c) {
  return __builtin_amdgcn_mfma_f32_16x16x32_bf16(a, b, c, 0, 0, 0);
}
// packed f32x2 -> bf16x2 (RNE), no builtin on gfx950 -> inline asm
__device__ __forceinline__ unsigned cvtpk(float a, float b) {
  unsigned r;
  asm("v_cvt_pk_bf16_f32 %0, %1, %2" : "=v"(r) : "v"(a), "v"(b));
  return r;
}
// gfx950 cross-lane row swaps (VALU, not LDS pipe).
__device__ __forceinline__ void swap32(unsigned& a, unsigned& b) {
  asm volatile("v_permlane32_swap_b32 %0, %1" : "+v"(a), "+v"(b));
}
__device__ __forceinline__ void swap16(unsigned& a, unsigned& b) {
  asm volatile("v_permlane16_swap_b32 %0, %1" : "+v"(a), "+v"(b));
}
// async global->LDS, 16B per lane. lds dest must be wave-uniform base + lane*16.
__device__ __forceinline__ void gload16(const unsigned short* g, unsigned short* l) {
  __builtin_amdgcn_global_load_lds(
      (const __attribute__((address_space(1))) void*)g,
      (__attribute__((address_space(3))) void*)l, 16, 0, 0);
}

// ---------------------------------------------------------------------------
// prep_all: flat-grid merge of all prep stages.
//   bid <  20          : prep_pack (factor, beff, bqkv)
//   20 <= bid < 1556   : wprep (Weff / Wq/Wk/Wv/Wo transpose-convert)
//   1556 <= bid < 3604 : cvt x -> bf16
//   bid >= 3604        : zero cemean+Vsum (4 blocks x 1024 floats)
// ---------------------------------------------------------------------------
__global__ __launch_bounds__(256) void prep_all(
    const float* __restrict__ x, const float* __restrict__ cons,
    const float* __restrict__ gate, const float* __restrict__ Wc,
    const float* __restrict__ bc,
    const float* __restrict__ bq, const float* __restrict__ bk,
    const float* __restrict__ bv,
    const float* __restrict__ W0, const float* __restrict__ W1,
    const float* __restrict__ W2, const float* __restrict__ W3,
    float* __restrict__ beff, float* __restrict__ bqkv,
    float* __restrict__ factor,
    unsigned short* __restrict__ Weft, unsigned short* __restrict__ Wqkvt,
    unsigned short* __restrict__ Wot, unsigned short* __restrict__ xbf,
    float* __restrict__ zbuf) {
  __shared__ float t[64][69];
  int bid = blockIdx.x;
  int tid = threadIdx.x;

  if (bid < 20) {
    // ---- prep_pack body ----
    int i = bid * 256 + tid;
    if (i == 0) {
      float gw[LL][HH];
      for (int l = 0; l < LL; ++l) {
        float mx = -1e30f;
        for (int h = 0; h < HH; ++h) mx = fmaxf(mx, gate[l * HH + h]);
        float s = 0.f;
        for (int h = 0; h < HH; ++h) { gw[l][h] = expf(gate[l * HH + h] - mx); s += gw[l][h]; }
        for (int h = 0; h < HH; ++h) gw[l][h] /= s;
      }
      for (int b = 0; b < BB; ++b)
        for (int h = 0; h < HH; ++h) {
          float f = 1.f;
          for (int l = 0; l < LL; ++l) f *= 1.f + 0.1f * cons[b * HH + l] * gw[l][h];
          factor[b * HH + h] = f;
        }
    }
    if (i < BB * EE) {
      int b = i >> 10, e = i & 1023;
      float a = 0.f;
      #pragma unroll
      for (int l = 0; l < LL; ++l) a += cons[b * HH + l] * bc[l * EE + e];
      beff[i] = a * (1.f / LL);
    } else {
      int j = i - BB * EE;  // 0..3071
      float v = (j < EE) ? bq[j] : (j < 2 * EE) ? bk[j - EE] : bv[j - 2 * EE];
      bqkv[j] = v;
    }
    return;
  }

  if (bid < 20 + 1536) {
    // ---- wprep body: idx -> (x,y,z) of the original (16,16,6) grid ----
    int idx = bid - 20;
    int gx = idx & 15, gy = (idx >> 4) & 15, z = idx >> 8;
    int o0 = gx * 64, e0 = gy * 64;
    if (z < 2) {
      int b = z;
      float w[LL];
      #pragma unroll
      for (int l = 0; l < LL; ++l) w[l] = cons[b * HH + l] * (1.f / LL);
      #pragma unroll
      for (int i = 0; i < 4; ++i) {
        int id2 = tid + i * 256;
        int r = id2 >> 4, c4 = id2 & 15;
        float4 acc = {0.f, 0.f, 0.f, 0.f};
        #pragma unroll
        for (int l = 0; l < LL; ++l) {
          float4 v = *(const float4*)&Wc[(long)l * EE * EE + (long)(e0 + r) * EE + o0 + c4 * 4];
          acc.x += w[l] * v.x; acc.y += w[l] * v.y; acc.z += w[l] * v.z; acc.w += w[l] * v.w;
        }
        t[r][c4 * 4 + 0] = acc.x; t[r][c4 * 4 + 1] = acc.y;
        t[r][c4 * 4 + 2] = acc.z; t[r][c4 * 4 + 3] = acc.w;
      }
    } else {
      const float* W = (z == 2) ? W0 : (z == 3) ? W1 : (z == 4) ? W2 : W3;
      #pragma unroll
      for (int i = 0; i < 4; ++i) {
        int id2 = tid + i * 256;
        int r = id2 >> 4, c4 = id2 & 15;
        float4 v = *(const float4*)&W[(long)(e0 + r) * EE + o0 + c4 * 4];
        t[r][c4 * 4 + 0] = v.x; t[r][c4 * 4 + 1] = v.y;
        t[r][c4 * 4 + 2] = v.z; t[r][c4 * 4 + 3] = v.w;
      }
    }
    __syncthreads();
    unsigned short* Wt = (z < 2) ? (Weft + (size_t)z * EE * EE)
                       : (z < 5) ? (Wqkvt + (size_t)(z - 2) * EE * EE)
                                 : Wot;
    #pragma unroll
    for (int i = 0; i < 2; ++i) {
      int id2 = tid + i * 256;
      int o = id2 >> 3, ech = id2 & 7;
      unsigned short u[8];
      #pragma unroll
      for (int j = 0; j < 8; ++j) u[j] = f2bf(t[ech * 8 + j][o]);
      unsigned short* dst = Wt + (long)(o0 + o) * EE + e0 + ech * 8;
      *(ushort4*)&dst[0] = *(ushort4*)&u[0];
      *(ushort4*)&dst[4] = *(ushort4*)&u[4];
    }
    return;
  }

  if (bid < 20 + 1536 + 2048) {
    // ---- cvt_bf body ----
    long i = (long)(bid - (20 + 1536)) * 256 + tid;
    float4 a = ((const float4*)x)[i * 2];
    float4 b = ((const float4*)x)[i * 2 + 1];
    ushort4 u0 = make_ushort4(f2bf(a.x), f2bf(a.y), f2bf(a.z), f2bf(a.w));
    ushort4 u1 = make_ushort4(f2bf(b.x), f2bf(b.y), f2bf(b.z), f2bf(b.w));
    ((ushort4*)xbf)[i * 2] = u0;
    ((ushort4*)xbf)[i * 2 + 1] = u1;
    return;
  }

  // ---- zero cemean+Vsum (4096 floats over 4 blocks) ----
  int i = (bid - (20 + 1536 + 2048)) * 1024 + tid * 4;
  *(float4*)&zbuf[i] = make_float4(0.f, 0.f, 0.f, 0.f);
}

// ---------------------------------------------------------------------------
// bf16 MFMA GEMM, 128x128 tile (m97 structure).
// VSPLIT=1: output columns >= 2048 (V of fused QKV) are written TRANSPOSED to
// Vt[bh][d][s]; their column sums (over s) are atomicAdd'ed into Faux (=Vsum).
// MEANOUT=1: per-column means (over rows) atomicAdd'ed into Faux (=cemean).
// ---------------------------------------------------------------------------
template <int OUTBF, int VSPLIT, int MEANOUT>
__global__ __launch_bounds__(256) void gemm128(
    const unsigned short* __restrict__ A, const unsigned short* __restrict__ Bt,
    const float* __restrict__ bias, void* __restrict__ C,
    unsigned short* __restrict__ VtOut, float* __restrict__ Faux,
    int N, int K, long As_z, long Ws_z, long Bs_z, long Cs_z) {
  int flat = blockIdx.x + gridDim.x * (blockIdx.y + gridDim.y * blockIdx.z);
  int nwg = gridDim.x * gridDim.y * gridDim.z;
  flat = (flat & 7) * (nwg >> 3) + (flat >> 3);
  int nt_ = flat % gridDim.x;
  int rest = flat / gridDim.x;
  int mt_ = rest % gridDim.y;
  int z = rest / gridDim.y;

  const unsigned short* Ab = A + z * As_z + (long)mt_ * 128 * K;
  const unsigned short* Bb = Bt + z * Ws_z + (long)nt_ * 128 * K;
  const float* bb = bias + z * Bs_z + nt_ * 128;

  __shared__ __align__(16) unsigned short As[2][128 * 64];
  __shared__ __align__(16) unsigned short Bs[2][128 * 64];
  int tid = threadIdx.x;
  int w = tid >> 6, lane = tid & 63, c = lane & 15, g = lane >> 4;
  int wrow = (w >> 1) * 64, wcol = (w & 1) * 64;

  #define STG128(srcp, dstbuf, kt)                                             \
    {                                                                          \
      const unsigned short* s_ = (srcp) + (kt) * 64;                           \
      _Pragma("unroll") for (int j = 0; j < 4; ++j) {                          \
        int idx = tid + j * 256;                                               \
        int row = idx >> 3, ch = idx & 7;                                      \
        gload16(s_ + (long)row * K + ((ch ^ (row & 7)) << 3),                  \
                &dstbuf[(idx & ~63) * 8 + (lane)*8]);                          \
      }                                                                        \
    }

  f32x4 acc[4][4];
  #pragma unroll
  for (int mi = 0; mi < 4; ++mi)
    #pragma unroll
    for (int ni = 0; ni < 4; ++ni) acc[mi][ni] = {0.f, 0.f, 0.f, 0.f};

  int nk = K >> 6;
  STG128(Ab, As[0], 0) STG128(Bb, Bs[0], 0)
  __syncthreads();
  int buf = 0;
  for (int kt = 0; kt < nk; ++kt) {
    if (kt + 1 < nk) { STG128(Ab, As[buf ^ 1], kt + 1) STG128(Bb, Bs[buf ^ 1], kt + 1) }
    #pragma unroll
    for (int kk = 0; kk < 2; ++kk) {
      bf16x8 af[4], bfv[4];
      #pragma unroll
      for (int mi = 0; mi < 4; ++mi) {
        int row = wrow + mi * 16 + c;
        af[mi] = *(const bf16x8*)&As[buf][row * 64 + ((((kk << 2) + g) ^ (row & 7)) << 3)];
      }
      #pragma unroll
      for (int ni = 0; ni < 4; ++ni) {
        int row = wcol + ni * 16 + c;
        bfv[ni] = *(const bf16x8*)&Bs[buf][row * 64 + ((((kk << 2) + g) ^ (row & 7)) << 3)];
      }
      #pragma unroll
      for (int mi = 0; mi < 4; ++mi)
        #pragma unroll
        for (int ni = 0; ni < 4; ++ni)
          acc[mi][ni] = mfma16(af[mi], bfv[ni], acc[mi][ni]);
    }
    __syncthreads();
    buf ^= 1;
  }

  float bval[4];
  #pragma unroll
  for (int ni = 0; ni < 4; ++ni) bval[ni] = bb[wcol + ni * 16 + c];

  if (MEANOUT) {
    // fused column-mean: per-thread 16-row partial, g-shfl reduce, 1 atomic.
    #pragma unroll
    for (int ni = 0; ni < 4; ++ni) {
      float colsum = 16.f * bval[ni];
      #pragma unroll
      for (int mi = 0; mi < 4; ++mi)
        colsum += (acc[mi][ni][0] + acc[mi][ni][1]) +
                  (acc[mi][ni][2] + acc[mi][ni][3]);
      colsum += __shfl_xor(colsum, 16);
      colsum += __shfl_xor(colsum, 32);
      if (g == 0) {
        long col = (long)nt_ * 128 + wcol + ni * 16 + c;
        atomicAdd(&Faux[z * EE + col], colsum * (1.f / SS));
      }
    }
  }

  if (VSPLIT && nt_ >= 16) {
    // V columns: write transposed bf16 into Vt[bh][d][s]; fuse Vsum (sum over s)
    #pragma unroll
    for (int mi = 0; mi < 4; ++mi) {
      long s0 = (long)mt_ * 128 + wrow + mi * 16 + g * 4;
      #pragma unroll
      for (int ni = 0; ni < 4; ++ni) {
        int vc = (nt_ - 16) * 128 + wcol + ni * 16 + c;
        int bh = z * HH + (vc >> 6);
        int d = vc & 63;
        float a0 = acc[mi][ni][0] + bval[ni];
        float a1 = acc[mi][ni][1] + bval[ni];
        float a2 = acc[mi][ni][2] + bval[ni];
        float a3 = acc[mi][ni][3] + bval[ni];
        *(uint2*)&VtOut[((long)bh * 64 + d) * SS + s0] =
            make_uint2(cvtpk(a0, a1), cvtpk(a2, a3));
      }
    }
    #pragma unroll
    for (int ni = 0; ni < 4; ++ni) {
      float vsum = 16.f * bval[ni];
      #pragma unroll
      for (int mi = 0; mi < 4; ++mi)
        vsum += (acc[mi][ni][0] + acc[mi][ni][1]) +
                (acc[mi][ni][2] + acc[mi][ni][3]);
      vsum += __shfl_xor(vsum, 16);
      vsum += __shfl_xor(vsum, 32);
      if (g == 0) {
        int vc = (nt_ - 16) * 128 + wcol + ni * 16 + c;
        atomicAdd(&Faux[(z * HH + (vc >> 6)) * 64 + (vc & 63)], vsum);
      }
    }
  } else {
    #pragma unroll
    for (int mi = 0; mi < 4; ++mi)
      #pragma unroll
      for (int ni = 0; ni < 4; ++ni) {
        long col = (long)nt_ * 128 + wcol + ni * 16 + c;
        #pragma unroll
        for (int r = 0; r < 4; ++r) {
          long row = (long)mt_ * 128 + wrow + mi * 16 + g * 4 + r;
          float v = acc[mi][ni][r] + bval[ni];
          if (OUTBF)
            ((unsigned short*)C)[z * Cs_z + row * N + col] = f2bf(v);
          else
            ((float*)C)[z * Cs_z + row * N + col] = v;
        }
      }
  }
  #undef STG128
}

// ---------------------------------------------------------------------------
// qkcw: merged qkmean + cw.  One block per (b,h).
// Phase 1: ci[j] = dot(cemean[b], Wqkvt[(j<64?Q:K) row h*64+(j&63)]) + bias,
//          j in [0,128); each of 4 waves wave-reduces 32 dots (lane = 16 elems).
// Phase 2: alpha[b,h] = 1 + sigmoid(gelu(ci@Wc1+bc1)@Wc2+bc2).
// ---------------------------------------------------------------------------
__global__ __launch_bounds__(256) void qkcw_kernel(
    const float* __restrict__ cemean, const unsigned short* __restrict__ Wqkvt,
    const float* __restrict__ bqkv,
    const float* __restrict__ Wc1, const float* __restrict__ bc1,
    const float* __restrict__ Wc2, const float* __restrict__ bc2,
    float* __restrict__ alpha) {
  int bh = blockIdx.x, b = bh / HH, h = bh % HH;
  __shared__ float ci[128];
  __shared__ float pr[4];
  int tid = threadIdx.x;
  int w = tid >> 6, lane = tid & 63;
  const float* cm = cemean + b * EE + lane * 16;
  // phase 1: wave w computes ci[w*32 .. w*32+31]
  for (int jo = 0; jo < 32; ++jo) {
    int j = w * 32 + jo;
    int col = h * 64 + (j & 63);
    const unsigned short* wrow =
        Wqkvt + ((j < 64) ? 0 : (size_t)EE * EE) + (long)col * EE + lane * 16;
    float acc = 0.f;
    #pragma unroll
    for (int i = 0; i < 2; ++i) {
      uint4 v = *(const uint4*)(wrow + i * 8);
      unsigned arr[4] = {v.x, v.y, v.z, v.w};
      #pragma unroll
      for (int jj = 0; jj < 4; ++jj) {
        acc += cm[i * 8 + 2 * jj] * bf2f((unsigned short)(arr[jj] & 0xffffu));
        acc += cm[i * 8 + 2 * jj + 1] * bf2f((unsigned short)(arr[jj] >> 16));
      }
    }
    #pragma unroll
    for (int off = 32; off; off >>= 1) acc += __shfl_xor(acc, off);
    if (lane == 0) ci[j] = acc + bqkv[((j < 64) ? 0 : EE) + col];
  }
  __syncthreads();
  // phase 2: cw body
  float part = 0.f;
  for (int j = tid; j < EE; j += 256) {
    float acc = bc1[j];
    #pragma unroll 8
    for (int i = 0; i < 128; ++i) acc += ci[i] * Wc1[i * EE + j];
    float ge = 0.5f * acc * (1.f + erff(acc * 0.70710678118654752f));
    part += ge * Wc2[j];
  }
  #pragma unroll
  for (int off = 32; off; off >>= 1) part += __shfl_xor(part, off);
  if ((tid & 63) == 0) pr[tid >> 6] = part;
  __syncthreads();
  if (tid == 0) {
    float tot = pr[0] + pr[1] + pr[2] + pr[3] + bc2[0];
    float cw = 1.f / (1.f + expf(-tot));
    alpha[bh] = 1.f + cw;
  }
}

// ---------------------------------------------------------------------------
// Linearized attention (round-17/18 proven config): P in registers via
// permlane swaps; __expf(s*scaleE) (fast v_exp path); LDS 16KB; t-split x2;
// 4 waves x 32 q; T14 reg-staged K/V.
// Partials: m1p[part][b][h][s] f32; Np[part][b][s][e] bf16.
// ---------------------------------------------------------------------------
__global__ __launch_bounds__(256, 4) void attn_lin(
    const unsigned short* __restrict__ QKV,  // [b][s][3072]
    const unsigned short* __restrict__ Vt,   // [bh][d][s]
    const float* __restrict__ alpha,
    unsigned short* __restrict__ Np0, unsigned short* __restrict__ Np1,
    float* __restrict__ m1p) {
  int flat = blockIdx.x;
  flat = (flat & 7) * 128 + (flat >> 3);  // chunked XCD remap, nwg=1024
  int qt = flat & 15, h = (flat >> 4) & 15, b = (flat >> 8) & 1, part = flat >> 9;
  int bh = b * HH + h;
  int tid = threadIdx.x;
  int l = tid & 63, w = tid >> 6, c = l & 15, g = l >> 4;
  __shared__ __align__(16) unsigned short kbuf[4096];      // 8 KB
  __shared__ __align__(16) unsigned short vbuf[4096];      // 8 KB

  const unsigned short* Kb_ =
      QKV + (long)b * SS * QS + EE + h * 64 + (long)part * 1024 * QS;
  const unsigned short* Vb_ = Vt + (long)bh * 64 * SS + part * 1024;
  unsigned short* Np = part ? Np1 : Np0;
  const float scaleE = alpha[bh] * 0.125f;  // (1+cw)/sqrt(64)
  const f32x4 zero4 = {0.f, 0.f, 0.f, 0.f};

  // Q fragments: 2 q-subblocks x 2 k-halves, loaded once from global.
  bf16x8 qf[2][2];
  {
    const unsigned short* qp =
        QKV + ((long)b * SS + qt * 128 + w * 32 + c) * QS + h * 64;
    qf[0][0] = *(const bf16x8*)(qp + 8 * g);
    qf[0][1] = *(const bf16x8*)(qp + 32 + 8 * g);
    qf[1][0] = *(const bf16x8*)(qp + 16 * QS + 8 * g);
    qf[1][1] = *(const bf16x8*)(qp + 16 * QS + 32 + 8 * g);
  }

  // staging addresses: 2 chunks/thread/operand, source chunk-XOR pre-swizzled
  int off1 = tid, off2 = tid + 256;
  int r1 = off1 >> 3, ch1 = ((off1 & 7) ^ (r1 & 7)) << 3;
  int r2 = off2 >> 3, ch2 = ((off2 & 7) ^ (r2 & 7)) << 3;
  const unsigned short* kg1 = Kb_ + (long)r1 * QS + ch1;
  const unsigned short* kg2 = Kb_ + (long)r2 * QS + ch2;
  const unsigned short* vg1 = Vb_ + (long)r1 * SS + ch1;
  const unsigned short* vg2 = Vb_ + (long)r2 * SS + ch2;

  // prologue: tile 0 -> regs -> LDS
  uint4 ks1 = *(const uint4*)kg1, ks2 = *(const uint4*)kg2;
  uint4 vs1 = *(const uint4*)vg1, vs2 = *(const uint4*)vg2;
  kg1 += (long)64 * QS; kg2 += (long)64 * QS; vg1 += 64; vg2 += 64;
  *(uint4*)&kbuf[off1 * 8] = ks1; *(uint4*)&kbuf[off2 * 8] = ks2;
  *(uint4*)&vbuf[off1 * 8] = vs1; *(uint4*)&vbuf[off2 * 8] = vs2;
  __syncthreads();

  f32x4 N1[4][2];
  #pragma unroll
  for (int d = 0; d < 4; ++d) { N1[d][0] = zero4; N1[d][1] = zero4; }
  float m1l0 = 0.f, m1l1 = 0.f;

  const int NT2 = 16;  // 1024 t / 64
  for (int t = 0; t < NT2; ++t) {
    if (t + 1 < NT2) {  // issue next-tile loads early (hide HBM under compute)
      ks1 = *(const uint4*)kg1; ks2 = *(const uint4*)kg2;
      vs1 = *(const uint4*)vg1; vs2 = *(const uint4*)vg2;
      kg1 += (long)64 * QS; kg2 += (long)64 * QS; vg1 += 64; vg2 += 64;
    }
    __builtin_amdgcn_s_setprio(1);
    #pragma unroll
    for (int half = 0; half < 2; ++half) {
      // QK^T for this 32-t half (mt = 2*half+mth); u = exp(scale*s); pack.
      unsigned sA[2][2], sB[2][2];  // [qb][mth]: sA = t{..0,1}, sB = t{..2,3}
      #pragma unroll
      for (int mth = 0; mth < 2; ++mth) {
        int mt = half * 2 + mth;
        int r = mt * 16 + c;
        bf16x8 a0 = *(const bf16x8*)&kbuf[r * 64 + ((g ^ (r & 7)) << 3)];
        bf16x8 a1 = *(const bf16x8*)&kbuf[r * 64 + (((4 + g) ^ (r & 7)) << 3)];
        #pragma unroll
        for (int qb = 0; qb < 2; ++qb) {
          f32x4 s = mfma16(a0, qf[qb][0], zero4);
          s = mfma16(a1, qf[qb][1], s);
          float u0 = __expf(s[0] * scaleE), u1 = __expf(s[1] * scaleE);
          float u2 = __expf(s[2] * scaleE), u3 = __expf(s[3] * scaleE);
          if (qb == 0) m1l0 += (u0 + u1) + (u2 + u3);
          else         m1l1 += (u0 + u1) + (u2 + u3);
          sA[qb][mth] = cvtpk(u0, u1);
          sB[qb][mth] = cvtpk(u2, u3);
        }
      }
      // In-register redistribution to PV B-fragment layout.
      bf16x8 pf[2];
      #pragma unroll
      for (int qb = 0; qb < 2; ++qb) {
        unsigned w0 = sA[qb][0], w2 = sA[qb][1];
        swap32(w0, w2); swap16(w0, w2);
        unsigned w1 = sB[qb][0], w3 = sB[qb][1];
        swap32(w1, w3); swap16(w1, w3);
        union { unsigned u[4]; bf16x8 hv; } pk;
        pk.u[0] = w0; pk.u[1] = w1; pk.u[2] = w2; pk.u[3] = w3;
        pf[qb] = pk.hv;
      }
      // PV for this t-half: N1[d][q] += V[d][t-half] * P[t-half][q]
      #pragma unroll
      for (int dblk = 0; dblk < 4; ++dblk) {
        int r = dblk * 16 + c;
        bf16x8 v = *(const bf16x8*)&vbuf[r * 64 + (((half * 4 + g) ^ (r & 7)) << 3)];
        N1[dblk][0] = mfma16(v, pf[0], N1[dblk][0]);
        N1[dblk][1] = mfma16(v, pf[1], N1[dblk][1]);
      }
    }
    __builtin_amdgcn_s_setprio(0);
    __syncthreads();  // all waves done reading kbuf/vbuf
    if (t + 1 < NT2) {  // write next tile (compiler inserts vmcnt wait)
      *(uint4*)&kbuf[off1 * 8] = ks1; *(uint4*)&kbuf[off2 * 8] = ks2;
      *(uint4*)&vbuf[off1 * 8] = vs1; *(uint4*)&vbuf[off2 * 8] = vs2;
    }
    __syncthreads();  // writes visible before next-tile reads
  }

  // m1 per q-col: reduce across the 4 g-lane-groups
  m1l0 += __shfl_xor(m1l0, 16); m1l0 += __shfl_xor(m1l0, 32);
  m1l1 += __shfl_xor(m1l1, 16); m1l1 += __shfl_xor(m1l1, 32);
  if (l < 16) {
    long mb = ((long)(part * BB + b) * HH + h) * SS + qt * 128 + w * 32;
    m1p[mb + c] = m1l0;
    m1p[mb + 16 + c] = m1l1;
  }

  #pragma unroll
  for (int qb = 0; qb < 2; ++qb) {
    unsigned short* np =
        Np + ((long)b * SS + qt * 128 + w * 32 + qb * 16 + c) * EE + h * 64;
    #pragma unroll
    for (int dblk = 0; dblk < 4; ++dblk) {
      *(uint2*)&np[dblk * 16 + 4 * g] =
          make_uint2(cvtpk(N1[dblk][qb][0], N1[dblk][qb][1]),
                     cvtpk(N1[dblk][qb][2], N1[dblk][qb][3]));
    }
  }
}

// ---------------------------------------------------------------------------
// Combine: att = bf16( (Vsum + f*(N0+N1)/(m1a+m1b)) / (2048+f) ).  Np bf16.
// ---------------------------------------------------------------------------
__global__ __launch_bounds__(256) void attn_combine(
    const unsigned short* __restrict__ Np0, const unsigned short* __restrict__ Np1,
    const float* __restrict__ m1p, const float* __restrict__ Vsum,
    const float* __restrict__ factor, unsigned short* __restrict__ att) {
  int row = blockIdx.x;  // b*SS + s
  int b = row >> 11, s = row & 2047;
  int e0 = threadIdx.x * 4;
  int h = e0 >> 6, d = e0 & 63;
  int bh = b * HH + h;
  float m1 = m1p[((long)b * HH + h) * SS + s] +
             m1p[((long)(BB + b) * HH + h) * SS + s];
  float fac = factor[bh];
  float c1 = fac / m1;
  float invden = 1.f / ((float)SS + fac);
  long base = (long)row * EE + e0;
  ushort4 a0 = *(const ushort4*)&Np0[base];
  ushort4 a1 = *(const ushort4*)&Np1[base];
  float4 vs = *(const float4*)&Vsum[bh * 64 + d];
  float n0 = bf2f(a0.x) + bf2f(a1.x);
  float n1 = bf2f(a0.y) + bf2f(a1.y);
  float n2 = bf2f(a0.z) + bf2f(a1.z);
  float n3 = bf2f(a0.w) + bf2f(a1.w);
  float o0 = (vs.x + c1 * n0) * invden;
  float o1 = (vs.y + c1 * n1) * invden;
  float o2 = (vs.z + c1 * n2) * invden;
  float o3 = (vs.w + c1 * n3) * invden;
  *(uint2*)&att[base] = make_uint2(cvtpk(o0, o1), cvtpk(o2, o3));
}

// ---------------------------------------------------------------------------
// LayerNorm(x + proj) * g + b.  proj bf16; thread owns 4 contiguous elems.
// ---------------------------------------------------------------------------
__global__ __launch_bounds__(256) void ln_kernel(
    const float* __restrict__ x, const unsigned short* __restrict__ proj,
    const float* __restrict__ g, const float* __restrict__ bb,
    float* __restrict__ out) {
  long row = blockIdx.x;
  const float* xp = x + row * EE;
  const unsigned short* pp = proj + row * EE;
  int tid = threadIdx.x;
  int e0 = tid * 4;
  float v[4];
  __shared__ float r1[4], r2[4];
  float4 xv = *(const float4*)&xp[e0];
  ushort4 pv = *(const ushort4*)&pp[e0];
  v[0] = xv.x + bf2f(pv.x);
  v[1] = xv.y + bf2f(pv.y);
  v[2] = xv.z + bf2f(pv.z);
  v[3] = xv.w + bf2f(pv.w);
  float s = (v[0] + v[1]) + (v[2] + v[3]);
  #pragma unroll
  for (int off = 32; off; off >>= 1) s += __shfl_xor(s, off);
  if ((tid & 63) == 0) r1[tid >> 6] = s;
  __syncthreads();
  float mean = (r1[0] + r1[1] + r1[2] + r1[3]) * (1.f / EE);
  float s2 = 0.f;
  #pragma unroll
  for (int i = 0; i < 4; ++i) { float d = v[i] - mean; s2 += d * d; }
  #pragma unroll
  for (int off = 32; off; off >>= 1) s2 += __shfl_xor(s2, off);
  if ((tid & 63) == 0) r2[tid >> 6] = s2;
  __syncthreads();
  float rstd = rsqrtf((r2[0] + r2[1] + r2[2] + r2[3]) * (1.f / EE) + 1e-5f);
  float4 gv = *(const float4*)&g[e0];
  float4 bv = *(const float4*)&bb[e0];
  float4 o;
  o.x = (v[0] - mean) * rstd * gv.x + bv.x;
  o.y = (v[1] - mean) * rstd * gv.y + bv.y;
  o.z = (v[2] - mean) * rstd * gv.z + bv.z;
  o.w = (v[3] - mean) * rstd * gv.w + bv.w;
  *(float4*)&out[row * EE + e0] = o;
}

// ---------------------------------------------------------------------------
extern "C" void kernel_launch(void* const* d_in, const int* in_sizes, int n_in,
                              void* d_out, int out_size, void* d_ws, size_t ws_size,
                              hipStream_t stream) {
  (void)in_sizes; (void)n_in; (void)out_size; (void)ws_size;
  const float* x    = (const float*)d_in[0];
  const float* cons = (const float*)d_in[1];
  const float* Wc   = (const float*)d_in[2];
  const float* bc   = (const float*)d_in[3];
  // d_in[4] Wf, d_in[5] bf, d_in[19] phi_phase: unused (phase term cancels)
  const float* Wq   = (const float*)d_in[6];
  const float* bq   = (const float*)d_in[7];
  const float* Wk   = (const float*)d_in[8];
  const float* bk   = (const float*)d_in[9];
  const float* Wv   = (const float*)d_in[10];
  const float* bv   = (const float*)d_in[11];
  const float* Wo   = (const float*)d_in[12];
  const float* bo   = (const float*)d_in[13];
  const float* Wc1  = (const float*)d_in[14];
  const float* bc1  = (const float*)d_in[15];
  const float* Wc2  = (const float*)d_in[16];
  const float* bc2  = (const float*)d_in[17];
  const float* gate = (const float*)d_in[18];
  const float* ln_g = (const float*)d_in[20];
  const float* ln_b = (const float*)d_in[21];
  float* out = (float*)d_out;

  const size_t MSZ = (size_t)BB * SS * EE;  // 4M elems
  float* p = (float*)d_ws;
  float* beff = p;  p += BB * EE;
  float* factor = p; p += 32;
  float* alpha  = p; p += 32;
  float* cemean = p; p += BB * EE;  // cemean + Vsum adjacent: zeroed in prep_all
  float* Vsum = p;  p += BB * EE;
  float* bqkv = p;  p += QS;
  unsigned short* projbf = (unsigned short*)p;  p += MSZ / 2;  // bf16 proj
  unsigned short* q = (unsigned short*)p;
  unsigned short* xbf  = q;  q += MSZ;
  unsigned short* cebf = q;  q += MSZ;
  unsigned short* QKVb = q;  q += 3 * MSZ;  // V third never written (diverted)
  unsigned short* Vt   = q;  q += MSZ;
  unsigned short* attb = q;  q += MSZ;
  unsigned short* Weft = q;  q += (size_t)BB * EE * EE;
  unsigned short* Wqkvt= q;  q += (size_t)3 * EE * EE;
  unsigned short* Wot  = q;  q += (size_t)EE * EE;
  float* m1p = (float*)q;    q += 2 * 2 * BB * HH * SS;  // [2][b][h][s] f32
  // bf16 N partials alias dead regions:
  unsigned short* Np0 = xbf;   // dead after ce gemm
  unsigned short* Np1 = cebf;  // dead after QKV gemm

  // merged prep: prep_pack (20) + wprep (1536) + cvt x->bf16 (2048)
  //            + zero cemean/Vsum (4) blocks
  prep_all<<<20 + 1536 + 2048 + 4, 256, 0, stream>>>(
      x, cons, gate, Wc, bc, bq, bk, bv, Wq, Wk, Wv, Wo,
      beff, bqkv, factor, Weft, Wqkvt, Wot, xbf, cemean);

  // ce = x @ Weff + beff  (bf16 out, 128x128 tile) + fused column-mean
  dim3 cgrid(EE / 128, SS / 128, BB);  // 8x16x2 = 256 wgs
  gemm128<1, 0, 1><<<cgrid, 256, 0, stream>>>(xbf, Weft, beff, cebf, nullptr,
                                              cemean, EE, EE, (long)SS * EE,
                                              (long)EE * EE, EE, (long)SS * EE);

  // QKV = ce @ [Wq|Wk|Wv] + [bq|bk|bv]; V diverted to Vt transposed + fused Vsum
  dim3 qgrid(QS / 128, SS / 128, BB);  // 24x16x2 = 768 wgs
  gemm128<1, 1, 0><<<qgrid, 256, 0, stream>>>(cebf, Wqkvt, bqkv, QKVb, Vt, Vsum,
                                              QS, EE, (long)SS * EE, 0, 0,
                                              (long)SS * QS);

  // alpha via merged qkmean+cw (one block per (b,h))
  qkcw_kernel<<<BB * HH, 256, 0, stream>>>(cemean, Wqkvt, bqkv, Wc1, bc1, Wc2,
                                           bc2, alpha);

  attn_lin<<<1024, 256, 0, stream>>>(QKVb, Vt, alpha, Np0, Np1, m1p);
  attn_combine<<<BB * SS, 256, 0, stream>>>(Np0, Np1, m1p, Vsum, factor, attb);

  // proj = att @ Wo + bo  (BF16 out, 128x128 tile)
  gemm128<1, 0, 0><<<cgrid, 256, 0, stream>>>(attb, Wot, bo, projbf, nullptr,
                                              nullptr, EE, EE, (long)SS * EE, 0,
                                              0, (long)SS * EE);
  ln_kernel<<<BB * SS, 256, 0, stream>>>(x, projbf, ln_g, ln_b, out);
}

// Round 24
// 190.851 us; speedup vs baseline: 1.0926x; 1.0926x over previous
//
#include <hip/hip_runtime.h>
#include <math.h>

#define BB 2
#define SS 2048
#define EE 1024
#define HH 16
#define LL 5
#define DH 64
#define QS (3 * 1024)  // QKV fused row stride

typedef __attribute__((ext_vector_type(8))) short bf16x8;
typedef __attribute__((ext_vector_type(4))) float f32x4;

__device__ __forceinline__ unsigned short f2bf(float f) {
  unsigned u = __float_as_uint(f);
  u += 0x7fffu + ((u >> 16) & 1u);
  return (unsigned short)(u >> 16);
}
__device__ __forceinline__ float bf2f(unsigned short u) {
  return __uint_as_float((unsigned)u << 16);
}
__device__ __forceinline__ f32x4 mfma16(bf16x8 a, bf16x8 b, f32x4 c) {
  return __builtin_amdgcn_mfma_f32_16x16x32_bf16(a, b, c, 0, 0, 0);
}
// packed f32x2 -> bf16x2 (RNE), no builtin on gfx950 -> inline asm
__device__ __forceinline__ unsigned cvtpk(float a, float b) {
  unsigned r;
  asm("v_cvt_pk_bf16_f32 %0, %1, %2" : "=v"(r) : "v"(a), "v"(b));
  return r;
}
// gfx950 cross-lane row swaps (VALU, not LDS pipe).
__device__ __forceinline__ void swap32(unsigned& a, unsigned& b) {
  asm volatile("v_permlane32_swap_b32 %0, %1" : "+v"(a), "+v"(b));
}
__device__ __forceinline__ void swap16(unsigned& a, unsigned& b) {
  asm volatile("v_permlane16_swap_b32 %0, %1" : "+v"(a), "+v"(b));
}
// async global->LDS, 16B per lane. lds dest must be wave-uniform base + lane*16.
__device__ __forceinline__ void gload16(const unsigned short* g, unsigned short* l) {
  __builtin_amdgcn_global_load_lds(
      (const __attribute__((address_space(1))) void*)g,
      (__attribute__((address_space(3))) void*)l, 16, 0, 0);
}

// ---------------------------------------------------------------------------
// prep_all: flat-grid merge of all prep stages.
//   bid <  20          : prep_pack (factor, beff, bqkv)
//   20 <= bid < 1556   : wprep (Weff / Wq/Wk/Wv/Wo transpose-convert)
//   1556 <= bid < 3604 : cvt x -> bf16
//   bid >= 3604        : zero cemean+Vsum (4 blocks x 1024 floats)
// ---------------------------------------------------------------------------
__global__ __launch_bounds__(256) void prep_all(
    const float* __restrict__ x, const float* __restrict__ cons,
    const float* __restrict__ gate, const float* __restrict__ Wc,
    const float* __restrict__ bc,
    const float* __restrict__ bq, const float* __restrict__ bk,
    const float* __restrict__ bv,
    const float* __restrict__ W0, const float* __restrict__ W1,
    const float* __restrict__ W2, const float* __restrict__ W3,
    float* __restrict__ beff, float* __restrict__ bqkv,
    float* __restrict__ factor,
    unsigned short* __restrict__ Weft, unsigned short* __restrict__ Wqkvt,
    unsigned short* __restrict__ Wot, unsigned short* __restrict__ xbf,
    float* __restrict__ zbuf) {
  __shared__ float t[64][69];
  int bid = blockIdx.x;
  int tid = threadIdx.x;

  if (bid < 20) {
    // ---- prep_pack body ----
    int i = bid * 256 + tid;
    if (i == 0) {
      float gw[LL][HH];
      for (int l = 0; l < LL; ++l) {
        float mx = -1e30f;
        for (int h = 0; h < HH; ++h) mx = fmaxf(mx, gate[l * HH + h]);
        float s = 0.f;
        for (int h = 0; h < HH; ++h) { gw[l][h] = expf(gate[l * HH + h] - mx); s += gw[l][h]; }
        for (int h = 0; h < HH; ++h) gw[l][h] /= s;
      }
      for (int b = 0; b < BB; ++b)
        for (int h = 0; h < HH; ++h) {
          float f = 1.f;
          for (int l = 0; l < LL; ++l) f *= 1.f + 0.1f * cons[b * HH + l] * gw[l][h];
          factor[b * HH + h] = f;
        }
    }
    if (i < BB * EE) {
      int b = i >> 10, e = i & 1023;
      float a = 0.f;
      #pragma unroll
      for (int l = 0; l < LL; ++l) a += cons[b * HH + l] * bc[l * EE + e];
      beff[i] = a * (1.f / LL);
    } else {
      int j = i - BB * EE;  // 0..3071
      float v = (j < EE) ? bq[j] : (j < 2 * EE) ? bk[j - EE] : bv[j - 2 * EE];
      bqkv[j] = v;
    }
    return;
  }

  if (bid < 20 + 1536) {
    // ---- wprep body: idx -> (x,y,z) of the original (16,16,6) grid ----
    int idx = bid - 20;
    int gx = idx & 15, gy = (idx >> 4) & 15, z = idx >> 8;
    int o0 = gx * 64, e0 = gy * 64;
    if (z < 2) {
      int b = z;
      float w[LL];
      #pragma unroll
      for (int l = 0; l < LL; ++l) w[l] = cons[b * HH + l] * (1.f / LL);
      #pragma unroll
      for (int i = 0; i < 4; ++i) {
        int id2 = tid + i * 256;
        int r = id2 >> 4, c4 = id2 & 15;
        float4 acc = {0.f, 0.f, 0.f, 0.f};
        #pragma unroll
        for (int l = 0; l < LL; ++l) {
          float4 v = *(const float4*)&Wc[(long)l * EE * EE + (long)(e0 + r) * EE + o0 + c4 * 4];
          acc.x += w[l] * v.x; acc.y += w[l] * v.y; acc.z += w[l] * v.z; acc.w += w[l] * v.w;
        }
        t[r][c4 * 4 + 0] = acc.x; t[r][c4 * 4 + 1] = acc.y;
        t[r][c4 * 4 + 2] = acc.z; t[r][c4 * 4 + 3] = acc.w;
      }
    } else {
      const float* W = (z == 2) ? W0 : (z == 3) ? W1 : (z == 4) ? W2 : W3;
      #pragma unroll
      for (int i = 0; i < 4; ++i) {
        int id2 = tid + i * 256;
        int r = id2 >> 4, c4 = id2 & 15;
        float4 v = *(const float4*)&W[(long)(e0 + r) * EE + o0 + c4 * 4];
        t[r][c4 * 4 + 0] = v.x; t[r][c4 * 4 + 1] = v.y;
        t[r][c4 * 4 + 2] = v.z; t[r][c4 * 4 + 3] = v.w;
      }
    }
    __syncthreads();
    unsigned short* Wt = (z < 2) ? (Weft + (size_t)z * EE * EE)
                       : (z < 5) ? (Wqkvt + (size_t)(z - 2) * EE * EE)
                                 : Wot;
    #pragma unroll
    for (int i = 0; i < 2; ++i) {
      int id2 = tid + i * 256;
      int o = id2 >> 3, ech = id2 & 7;
      unsigned short u[8];
      #pragma unroll
      for (int j = 0; j < 8; ++j) u[j] = f2bf(t[ech * 8 + j][o]);
      unsigned short* dst = Wt + (long)(o0 + o) * EE + e0 + ech * 8;
      *(ushort4*)&dst[0] = *(ushort4*)&u[0];
      *(ushort4*)&dst[4] = *(ushort4*)&u[4];
    }
    return;
  }

  if (bid < 20 + 1536 + 2048) {
    // ---- cvt_bf body ----
    long i = (long)(bid - (20 + 1536)) * 256 + tid;
    float4 a = ((const float4*)x)[i * 2];
    float4 b = ((const float4*)x)[i * 2 + 1];
    ushort4 u0 = make_ushort4(f2bf(a.x), f2bf(a.y), f2bf(a.z), f2bf(a.w));
    ushort4 u1 = make_ushort4(f2bf(b.x), f2bf(b.y), f2bf(b.z), f2bf(b.w));
    ((ushort4*)xbf)[i * 2] = u0;
    ((ushort4*)xbf)[i * 2 + 1] = u1;
    return;
  }

  // ---- zero cemean+Vsum (4096 floats over 4 blocks) ----
  int i = (bid - (20 + 1536 + 2048)) * 1024 + tid * 4;
  *(float4*)&zbuf[i] = make_float4(0.f, 0.f, 0.f, 0.f);
}

// ---------------------------------------------------------------------------
// bf16 MFMA GEMM, 128x128 tile (m97 structure).
// VSPLIT=1: output columns >= 2048 (V of fused QKV) are written TRANSPOSED to
// Vt[bh][d][s]; their column sums (over s) are atomicAdd'ed into Faux (=Vsum).
// MEANOUT=1: per-column means (over rows) atomicAdd'ed into Faux (=cemean).
// ---------------------------------------------------------------------------
template <int OUTBF, int VSPLIT, int MEANOUT>
__global__ __launch_bounds__(256) void gemm128(
    const unsigned short* __restrict__ A, const unsigned short* __restrict__ Bt,
    const float* __restrict__ bias, void* __restrict__ C,
    unsigned short* __restrict__ VtOut, float* __restrict__ Faux,
    int N, int K, long As_z, long Ws_z, long Bs_z, long Cs_z) {
  int flat = blockIdx.x + gridDim.x * (blockIdx.y + gridDim.y * blockIdx.z);
  int nwg = gridDim.x * gridDim.y * gridDim.z;
  flat = (flat & 7) * (nwg >> 3) + (flat >> 3);
  int nt_ = flat % gridDim.x;
  int rest = flat / gridDim.x;
  int mt_ = rest % gridDim.y;
  int z = rest / gridDim.y;

  const unsigned short* Ab = A + z * As_z + (long)mt_ * 128 * K;
  const unsigned short* Bb = Bt + z * Ws_z + (long)nt_ * 128 * K;
  const float* bb = bias + z * Bs_z + nt_ * 128;

  __shared__ __align__(16) unsigned short As[2][128 * 64];
  __shared__ __align__(16) unsigned short Bs[2][128 * 64];
  int tid = threadIdx.x;
  int w = tid >> 6, lane = tid & 63, c = lane & 15, g = lane >> 4;
  int wrow = (w >> 1) * 64, wcol = (w & 1) * 64;

  #define STG128(srcp, dstbuf, kt)                                             \
    {                                                                          \
      const unsigned short* s_ = (srcp) + (kt) * 64;                           \
      _Pragma("unroll") for (int j = 0; j < 4; ++j) {                          \
        int idx = tid + j * 256;                                               \
        int row = idx >> 3, ch = idx & 7;                                      \
        gload16(s_ + (long)row * K + ((ch ^ (row & 7)) << 3),                  \
                &dstbuf[(idx & ~63) * 8 + (lane)*8]);                          \
      }                                                                        \
    }

  f32x4 acc[4][4];
  #pragma unroll
  for (int mi = 0; mi < 4; ++mi)
    #pragma unroll
    for (int ni = 0; ni < 4; ++ni) acc[mi][ni] = {0.f, 0.f, 0.f, 0.f};

  int nk = K >> 6;
  STG128(Ab, As[0], 0) STG128(Bb, Bs[0], 0)
  __syncthreads();
  int buf = 0;
  for (int kt = 0; kt < nk; ++kt) {
    if (kt + 1 < nk) { STG128(Ab, As[buf ^ 1], kt + 1) STG128(Bb, Bs[buf ^ 1], kt + 1) }
    #pragma unroll
    for (int kk = 0; kk < 2; ++kk) {
      bf16x8 af[4], bfv[4];
      #pragma unroll
      for (int mi = 0; mi < 4; ++mi) {
        int row = wrow + mi * 16 + c;
        af[mi] = *(const bf16x8*)&As[buf][row * 64 + ((((kk << 2) + g) ^ (row & 7)) << 3)];
      }
      #pragma unroll
      for (int ni = 0; ni < 4; ++ni) {
        int row = wcol + ni * 16 + c;
        bfv[ni] = *(const bf16x8*)&Bs[buf][row * 64 + ((((kk << 2) + g) ^ (row & 7)) << 3)];
      }
      #pragma unroll
      for (int mi = 0; mi < 4; ++mi)
        #pragma unroll
        for (int ni = 0; ni < 4; ++ni)
          acc[mi][ni] = mfma16(af[mi], bfv[ni], acc[mi][ni]);
    }
    __syncthreads();
    buf ^= 1;
  }

  float bval[4];
  #pragma unroll
  for (int ni = 0; ni < 4; ++ni) bval[ni] = bb[wcol + ni * 16 + c];

  if (MEANOUT) {
    // fused column-mean: per-thread 16-row partial, g-shfl reduce, 1 atomic.
    #pragma unroll
    for (int ni = 0; ni < 4; ++ni) {
      float colsum = 16.f * bval[ni];
      #pragma unroll
      for (int mi = 0; mi < 4; ++mi)
        colsum += (acc[mi][ni][0] + acc[mi][ni][1]) +
                  (acc[mi][ni][2] + acc[mi][ni][3]);
      colsum += __shfl_xor(colsum, 16);
      colsum += __shfl_xor(colsum, 32);
      if (g == 0) {
        long col = (long)nt_ * 128 + wcol + ni * 16 + c;
        atomicAdd(&Faux[z * EE + col], colsum * (1.f / SS));
      }
    }
  }

  if (VSPLIT && nt_ >= 16) {
    // V columns: write transposed bf16 into Vt[bh][d][s]; fuse Vsum (sum over s)
    #pragma unroll
    for (int mi = 0; mi < 4; ++mi) {
      long s0 = (long)mt_ * 128 + wrow + mi * 16 + g * 4;
      #pragma unroll
      for (int ni = 0; ni < 4; ++ni) {
        int vc = (nt_ - 16) * 128 + wcol + ni * 16 + c;
        int bh = z * HH + (vc >> 6);
        int d = vc & 63;
        float a0 = acc[mi][ni][0] + bval[ni];
        float a1 = acc[mi][ni][1] + bval[ni];
        float a2 = acc[mi][ni][2] + bval[ni];
        float a3 = acc[mi][ni][3] + bval[ni];
        *(uint2*)&VtOut[((long)bh * 64 + d) * SS + s0] =
            make_uint2(cvtpk(a0, a1), cvtpk(a2, a3));
      }
    }
    #pragma unroll
    for (int ni = 0; ni < 4; ++ni) {
      float vsum = 16.f * bval[ni];
      #pragma unroll
      for (int mi = 0; mi < 4; ++mi)
        vsum += (acc[mi][ni][0] + acc[mi][ni][1]) +
                (acc[mi][ni][2] + acc[mi][ni][3]);
      vsum += __shfl_xor(vsum, 16);
      vsum += __shfl_xor(vsum, 32);
      if (g == 0) {
        int vc = (nt_ - 16) * 128 + wcol + ni * 16 + c;
        atomicAdd(&Faux[(z * HH + (vc >> 6)) * 64 + (vc & 63)], vsum);
      }
    }
  } else {
    #pragma unroll
    for (int mi = 0; mi < 4; ++mi)
      #pragma unroll
      for (int ni = 0; ni < 4; ++ni) {
        long col = (long)nt_ * 128 + wcol + ni * 16 + c;
        #pragma unroll
        for (int r = 0; r < 4; ++r) {
          long row = (long)mt_ * 128 + wrow + mi * 16 + g * 4 + r;
          float v = acc[mi][ni][r] + bval[ni];
          if (OUTBF)
            ((unsigned short*)C)[z * Cs_z + row * N + col] = f2bf(v);
          else
            ((float*)C)[z * Cs_z + row * N + col] = v;
        }
      }
  }
  #undef STG128
}

// ---------------------------------------------------------------------------
// qkmean: qkm[b][j] = (cemean @ [Wq|Wk] + [bq|bk])[j].  One WAVE per output.
// ---------------------------------------------------------------------------
__global__ __launch_bounds__(256) void qkmean_kernel(
    const float* __restrict__ cemean, const unsigned short* __restrict__ Wqkvt,
    const float* __restrict__ bqkv, float* __restrict__ qkm) {
  int o = blockIdx.x * 4 + (threadIdx.x >> 6);  // 0..4095
  int lane = threadIdx.x & 63;
  int b = o >> 11, j = o & 2047;
  int col = j & 1023;
  const unsigned short* wrow =
      Wqkvt + ((j < 1024) ? 0 : (size_t)EE * EE) + (long)col * EE + lane * 16;
  const float* cm = cemean + b * EE + lane * 16;
  float acc = 0.f;
  #pragma unroll
  for (int i = 0; i < 2; ++i) {
    uint4 v = *(const uint4*)(wrow + i * 8);
    unsigned arr[4] = {v.x, v.y, v.z, v.w};
    #pragma unroll
    for (int jj = 0; jj < 4; ++jj) {
      acc += cm[i * 8 + 2 * jj] * bf2f((unsigned short)(arr[jj] & 0xffffu));
      acc += cm[i * 8 + 2 * jj + 1] * bf2f((unsigned short)(arr[jj] >> 16));
    }
  }
  #pragma unroll
  for (int off = 32; off; off >>= 1) acc += __shfl_xor(acc, off);
  if (lane == 0) qkm[o] = acc + bqkv[((j < 1024) ? 0 : EE) + col];
}

// ---------------------------------------------------------------------------
// cw: alpha[b,h] = 1 + sigmoid(gelu(ci@Wc1+bc1)@Wc2+bc2); ci from qkm.
// ---------------------------------------------------------------------------
__global__ __launch_bounds__(256) void cw_kernel(
    const float* __restrict__ qkm,
    const float* __restrict__ Wc1, const float* __restrict__ bc1,
    const float* __restrict__ Wc2, const float* __restrict__ bc2,
    float* __restrict__ alpha) {
  int bh = blockIdx.x, b = bh / HH, h = bh % HH;
  __shared__ float ci[128];
  __shared__ float pr[4];
  int tid = threadIdx.x;
  if (tid < 128)
    ci[tid] = qkm[b * 2048 + ((tid < 64) ? 0 : 1024) + h * 64 + (tid & 63)];
  __syncthreads();
  float part = 0.f;
  for (int j = tid; j < EE; j += 256) {
    float acc = bc1[j];
    #pragma unroll 8
    for (int i = 0; i < 128; ++i) acc += ci[i] * Wc1[i * EE + j];
    float ge = 0.5f * acc * (1.f + erff(acc * 0.70710678118654752f));
    part += ge * Wc2[j];
  }
  #pragma unroll
  for (int off = 32; off; off >>= 1) part += __shfl_xor(part, off);
  if ((tid & 63) == 0) pr[tid >> 6] = part;
  __syncthreads();
  if (tid == 0) {
    float tot = pr[0] + pr[1] + pr[2] + pr[3] + bc2[0];
    float cw = 1.f / (1.f + expf(-tot));
    alpha[bh] = 1.f + cw;
  }
}

// ---------------------------------------------------------------------------
// Linearized attention (round-17/18 proven config): P in registers via
// permlane swaps; __expf(s*scaleE) (fast v_exp path); LDS 16KB; t-split x2;
// 4 waves x 32 q; T14 reg-staged K/V.
// Partials: m1p[part][b][h][s] f32; Np[part][b][s][e] bf16.
// ---------------------------------------------------------------------------
__global__ __launch_bounds__(256, 4) void attn_lin(
    const unsigned short* __restrict__ QKV,  // [b][s][3072]
    const unsigned short* __restrict__ Vt,   // [bh][d][s]
    const float* __restrict__ alpha,
    unsigned short* __restrict__ Np0, unsigned short* __restrict__ Np1,
    float* __restrict__ m1p) {
  int flat = blockIdx.x;
  flat = (flat & 7) * 128 + (flat >> 3);  // chunked XCD remap, nwg=1024
  int qt = flat & 15, h = (flat >> 4) & 15, b = (flat >> 8) & 1, part = flat >> 9;
  int bh = b * HH + h;
  int tid = threadIdx.x;
  int l = tid & 63, w = tid >> 6, c = l & 15, g = l >> 4;
  __shared__ __align__(16) unsigned short kbuf[4096];      // 8 KB
  __shared__ __align__(16) unsigned short vbuf[4096];      // 8 KB

  const unsigned short* Kb_ =
      QKV + (long)b * SS * QS + EE + h * 64 + (long)part * 1024 * QS;
  const unsigned short* Vb_ = Vt + (long)bh * 64 * SS + part * 1024;
  unsigned short* Np = part ? Np1 : Np0;
  const float scaleE = alpha[bh] * 0.125f;  // (1+cw)/sqrt(64)
  const f32x4 zero4 = {0.f, 0.f, 0.f, 0.f};

  // Q fragments: 2 q-subblocks x 2 k-halves, loaded once from global.
  bf16x8 qf[2][2];
  {
    const unsigned short* qp =
        QKV + ((long)b * SS + qt * 128 + w * 32 + c) * QS + h * 64;
    qf[0][0] = *(const bf16x8*)(qp + 8 * g);
    qf[0][1] = *(const bf16x8*)(qp + 32 + 8 * g);
    qf[1][0] = *(const bf16x8*)(qp + 16 * QS + 8 * g);
    qf[1][1] = *(const bf16x8*)(qp + 16 * QS + 32 + 8 * g);
  }

  // staging addresses: 2 chunks/thread/operand, source chunk-XOR pre-swizzled
  int off1 = tid, off2 = tid + 256;
  int r1 = off1 >> 3, ch1 = ((off1 & 7) ^ (r1 & 7)) << 3;
  int r2 = off2 >> 3, ch2 = ((off2 & 7) ^ (r2 & 7)) << 3;
  const unsigned short* kg1 = Kb_ + (long)r1 * QS + ch1;
  const unsigned short* kg2 = Kb_ + (long)r2 * QS + ch2;
  const unsigned short* vg1 = Vb_ + (long)r1 * SS + ch1;
  const unsigned short* vg2 = Vb_ + (long)r2 * SS + ch2;

  // prologue: tile 0 -> regs -> LDS
  uint4 ks1 = *(const uint4*)kg1, ks2 = *(const uint4*)kg2;
  uint4 vs1 = *(const uint4*)vg1, vs2 = *(const uint4*)vg2;
  kg1 += (long)64 * QS; kg2 += (long)64 * QS; vg1 += 64; vg2 += 64;
  *(uint4*)&kbuf[off1 * 8] = ks1; *(uint4*)&kbuf[off2 * 8] = ks2;
  *(uint4*)&vbuf[off1 * 8] = vs1; *(uint4*)&vbuf[off2 * 8] = vs2;
  __syncthreads();

  f32x4 N1[4][2];
  #pragma unroll
  for (int d = 0; d < 4; ++d) { N1[d][0] = zero4; N1[d][1] = zero4; }
  float m1l0 = 0.f, m1l1 = 0.f;

  const int NT2 = 16;  // 1024 t / 64
  for (int t = 0; t < NT2; ++t) {
    if (t + 1 < NT2) {  // issue next-tile loads early (hide HBM under compute)
      ks1 = *(const uint4*)kg1; ks2 = *(const uint4*)kg2;
      vs1 = *(const uint4*)vg1; vs2 = *(const uint4*)vg2;
      kg1 += (long)64 * QS; kg2 += (long)64 * QS; vg1 += 64; vg2 += 64;
    }
    __builtin_amdgcn_s_setprio(1);
    #pragma unroll
    for (int half = 0; half < 2; ++half) {
      // QK^T for this 32-t half (mt = 2*half+mth); u = exp(scale*s); pack.
      unsigned sA[2][2], sB[2][2];  // [qb][mth]: sA = t{..0,1}, sB = t{..2,3}
      #pragma unroll
      for (int mth = 0; mth < 2; ++mth) {
        int mt = half * 2 + mth;
        int r = mt * 16 + c;
        bf16x8 a0 = *(const bf16x8*)&kbuf[r * 64 + ((g ^ (r & 7)) << 3)];
        bf16x8 a1 = *(const bf16x8*)&kbuf[r * 64 + (((4 + g) ^ (r & 7)) << 3)];
        #pragma unroll
        for (int qb = 0; qb < 2; ++qb) {
          f32x4 s = mfma16(a0, qf[qb][0], zero4);
          s = mfma16(a1, qf[qb][1], s);
          float u0 = __expf(s[0] * scaleE), u1 = __expf(s[1] * scaleE);
          float u2 = __expf(s[2] * scaleE), u3 = __expf(s[3] * scaleE);
          if (qb == 0) m1l0 += (u0 + u1) + (u2 + u3);
          else         m1l1 += (u0 + u1) + (u2 + u3);
          sA[qb][mth] = cvtpk(u0, u1);
          sB[qb][mth] = cvtpk(u2, u3);
        }
      }
      // In-register redistribution to PV B-fragment layout.
      bf16x8 pf[2];
      #pragma unroll
      for (int qb = 0; qb < 2; ++qb) {
        unsigned w0 = sA[qb][0], w2 = sA[qb][1];
        swap32(w0, w2); swap16(w0, w2);
        unsigned w1 = sB[qb][0], w3 = sB[qb][1];
        swap32(w1, w3); swap16(w1, w3);
        union { unsigned u[4]; bf16x8 hv; } pk;
        pk.u[0] = w0; pk.u[1] = w1; pk.u[2] = w2; pk.u[3] = w3;
        pf[qb] = pk.hv;
      }
      // PV for this t-half: N1[d][q] += V[d][t-half] * P[t-half][q]
      #pragma unroll
      for (int dblk = 0; dblk < 4; ++dblk) {
        int r = dblk * 16 + c;
        bf16x8 v = *(const bf16x8*)&vbuf[r * 64 + (((half * 4 + g) ^ (r & 7)) << 3)];
        N1[dblk][0] = mfma16(v, pf[0], N1[dblk][0]);
        N1[dblk][1] = mfma16(v, pf[1], N1[dblk][1]);
      }
    }
    __builtin_amdgcn_s_setprio(0);
    __syncthreads();  // all waves done reading kbuf/vbuf
    if (t + 1 < NT2) {  // write next tile (compiler inserts vmcnt wait)
      *(uint4*)&kbuf[off1 * 8] = ks1; *(uint4*)&kbuf[off2 * 8] = ks2;
      *(uint4*)&vbuf[off1 * 8] = vs1; *(uint4*)&vbuf[off2 * 8] = vs2;
    }
    __syncthreads();  // writes visible before next-tile reads
  }

  // m1 per q-col: reduce across the 4 g-lane-groups
  m1l0 += __shfl_xor(m1l0, 16); m1l0 += __shfl_xor(m1l0, 32);
  m1l1 += __shfl_xor(m1l1, 16); m1l1 += __shfl_xor(m1l1, 32);
  if (l < 16) {
    long mb = ((long)(part * BB + b) * HH + h) * SS + qt * 128 + w * 32;
    m1p[mb + c] = m1l0;
    m1p[mb + 16 + c] = m1l1;
  }

  #pragma unroll
  for (int qb = 0; qb < 2; ++qb) {
    unsigned short* np =
        Np + ((long)b * SS + qt * 128 + w * 32 + qb * 16 + c) * EE + h * 64;
    #pragma unroll
    for (int dblk = 0; dblk < 4; ++dblk) {
      *(uint2*)&np[dblk * 16 + 4 * g] =
          make_uint2(cvtpk(N1[dblk][qb][0], N1[dblk][qb][1]),
                     cvtpk(N1[dblk][qb][2], N1[dblk][qb][3]));
    }
  }
}

// ---------------------------------------------------------------------------
// Combine: att = bf16( (Vsum + f*(N0+N1)/(m1a+m1b)) / (2048+f) ).  Np bf16.
// ---------------------------------------------------------------------------
__global__ __launch_bounds__(256) void attn_combine(
    const unsigned short* __restrict__ Np0, const unsigned short* __restrict__ Np1,
    const float* __restrict__ m1p, const float* __restrict__ Vsum,
    const float* __restrict__ factor, unsigned short* __restrict__ att) {
  int row = blockIdx.x;  // b*SS + s
  int b = row >> 11, s = row & 2047;
  int e0 = threadIdx.x * 4;
  int h = e0 >> 6, d = e0 & 63;
  int bh = b * HH + h;
  float m1 = m1p[((long)b * HH + h) * SS + s] +
             m1p[((long)(BB + b) * HH + h) * SS + s];
  float fac = factor[bh];
  float c1 = fac / m1;
  float invden = 1.f / ((float)SS + fac);
  long base = (long)row * EE + e0;
  ushort4 a0 = *(const ushort4*)&Np0[base];
  ushort4 a1 = *(const ushort4*)&Np1[base];
  float4 vs = *(const float4*)&Vsum[bh * 64 + d];
  float n0 = bf2f(a0.x) + bf2f(a1.x);
  float n1 = bf2f(a0.y) + bf2f(a1.y);
  float n2 = bf2f(a0.z) + bf2f(a1.z);
  float n3 = bf2f(a0.w) + bf2f(a1.w);
  float o0 = (vs.x + c1 * n0) * invden;
  float o1 = (vs.y + c1 * n1) * invden;
  float o2 = (vs.z + c1 * n2) * invden;
  float o3 = (vs.w + c1 * n3) * invden;
  *(uint2*)&att[base] = make_uint2(cvtpk(o0, o1), cvtpk(o2, o3));
}

// ---------------------------------------------------------------------------
// LayerNorm(x + proj) * g + b.  proj bf16; thread owns 4 contiguous elems.
// ---------------------------------------------------------------------------
__global__ __launch_bounds__(256) void ln_kernel(
    const float* __restrict__ x, const unsigned short* __restrict__ proj,
    const float* __restrict__ g, const float* __restrict__ bb,
    float* __restrict__ out) {
  long row = blockIdx.x;
  const float* xp = x + row * EE;
  const unsigned short* pp = proj + row * EE;
  int tid = threadIdx.x;
  int e0 = tid * 4;
  float v[4];
  __shared__ float r1[4], r2[4];
  float4 xv = *(const float4*)&xp[e0];
  ushort4 pv = *(const ushort4*)&pp[e0];
  v[0] = xv.x + bf2f(pv.x);
  v[1] = xv.y + bf2f(pv.y);
  v[2] = xv.z + bf2f(pv.z);
  v[3] = xv.w + bf2f(pv.w);
  float s = (v[0] + v[1]) + (v[2] + v[3]);
  #pragma unroll
  for (int off = 32; off; off >>= 1) s += __shfl_xor(s, off);
  if ((tid & 63) == 0) r1[tid >> 6] = s;
  __syncthreads();
  float mean = (r1[0] + r1[1] + r1[2] + r1[3]) * (1.f / EE);
  float s2 = 0.f;
  #pragma unroll
  for (int i = 0; i < 4; ++i) { float d = v[i] - mean; s2 += d * d; }
  #pragma unroll
  for (int off = 32; off; off >>= 1) s2 += __shfl_xor(s2, off);
  if ((tid & 63) == 0) r2[tid >> 6] = s2;
  __syncthreads();
  float rstd = rsqrtf((r2[0] + r2[1] + r2[2] + r2[3]) * (1.f / EE) + 1e-5f);
  float4 gv = *(const float4*)&g[e0];
  float4 bv = *(const float4*)&bb[e0];
  float4 o;
  o.x = (v[0] - mean) * rstd * gv.x + bv.x;
  o.y = (v[1] - mean) * rstd * gv.y + bv.y;
  o.z = (v[2] - mean) * rstd * gv.z + bv.z;
  o.w = (v[3] - mean) * rstd * gv.w + bv.w;
  *(float4*)&out[row * EE + e0] = o;
}

// ---------------------------------------------------------------------------
extern "C" void kernel_launch(void* const* d_in, const int* in_sizes, int n_in,
                              void* d_out, int out_size, void* d_ws, size_t ws_size,
                              hipStream_t stream) {
  (void)in_sizes; (void)n_in; (void)out_size; (void)ws_size;
  const float* x    = (const float*)d_in[0];
  const float* cons = (const float*)d_in[1];
  const float* Wc   = (const float*)d_in[2];
  const float* bc   = (const float*)d_in[3];
  // d_in[4] Wf, d_in[5] bf, d_in[19] phi_phase: unused (phase term cancels)
  const float* Wq   = (const float*)d_in[6];
  const float* bq   = (const float*)d_in[7];
  const float* Wk   = (const float*)d_in[8];
  const float* bk   = (const float*)d_in[9];
  const float* Wv   = (const float*)d_in[10];
  const float* bv   = (const float*)d_in[11];
  const float* Wo   = (const float*)d_in[12];
  const float* bo   = (const float*)d_in[13];
  const float* Wc1  = (const float*)d_in[14];
  const float* bc1  = (const float*)d_in[15];
  const float* Wc2  = (const float*)d_in[16];
  const float* bc2  = (const float*)d_in[17];
  const float* gate = (const float*)d_in[18];
  const float* ln_g = (const float*)d_in[20];
  const float* ln_b = (const float*)d_in[21];
  float* out = (float*)d_out;

  const size_t MSZ = (size_t)BB * SS * EE;  // 4M elems
  float* p = (float*)d_ws;
  float* beff = p;  p += BB * EE;
  float* factor = p; p += 32;
  float* alpha  = p; p += 32;
  float* cemean = p; p += BB * EE;  // cemean + Vsum adjacent: zeroed in prep_all
  float* Vsum = p;  p += BB * EE;
  float* qkm  = p;  p += BB * 2 * EE;
  float* bqkv = p;  p += QS;
  unsigned short* projbf = (unsigned short*)p;  p += MSZ / 2;  // bf16 proj
  unsigned short* q = (unsigned short*)p;
  unsigned short* xbf  = q;  q += MSZ;
  unsigned short* cebf = q;  q += MSZ;
  unsigned short* QKVb = q;  q += 3 * MSZ;  // V third never written (diverted)
  unsigned short* Vt   = q;  q += MSZ;
  unsigned short* attb = q;  q += MSZ;
  unsigned short* Weft = q;  q += (size_t)BB * EE * EE;
  unsigned short* Wqkvt= q;  q += (size_t)3 * EE * EE;
  unsigned short* Wot  = q;  q += (size_t)EE * EE;
  float* m1p = (float*)q;    q += 2 * 2 * BB * HH * SS;  // [2][b][h][s] f32
  // bf16 N partials alias dead regions:
  unsigned short* Np0 = xbf;   // dead after ce gemm
  unsigned short* Np1 = cebf;  // dead after QKV gemm

  // merged prep: prep_pack (20) + wprep (1536) + cvt x->bf16 (2048)
  //            + zero cemean/Vsum (4) blocks
  prep_all<<<20 + 1536 + 2048 + 4, 256, 0, stream>>>(
      x, cons, gate, Wc, bc, bq, bk, bv, Wq, Wk, Wv, Wo,
      beff, bqkv, factor, Weft, Wqkvt, Wot, xbf, cemean);

  // ce = x @ Weff + beff  (bf16 out, 128x128 tile) + fused column-mean
  dim3 cgrid(EE / 128, SS / 128, BB);  // 8x16x2 = 256 wgs
  gemm128<1, 0, 1><<<cgrid, 256, 0, stream>>>(xbf, Weft, beff, cebf, nullptr,
                                              cemean, EE, EE, (long)SS * EE,
                                              (long)EE * EE, EE, (long)SS * EE);

  // QKV = ce @ [Wq|Wk|Wv] + [bq|bk|bv]; V diverted to Vt transposed + fused Vsum
  dim3 qgrid(QS / 128, SS / 128, BB);  // 24x16x2 = 768 wgs
  gemm128<1, 1, 0><<<qgrid, 256, 0, stream>>>(cebf, Wqkvt, bqkv, QKVb, Vt, Vsum,
                                              QS, EE, (long)SS * EE, 0, 0,
                                              (long)SS * QS);

  // qkm = cemean @ [Wq|Wk] + [bq|bk]  (wave-per-output GEMV), then cw
  qkmean_kernel<<<(BB * 2 * EE) / 4, 256, 0, stream>>>(cemean, Wqkvt, bqkv, qkm);
  cw_kernel<<<BB * HH, 256, 0, stream>>>(qkm, Wc1, bc1, Wc2, bc2, alpha);

  attn_lin<<<1024, 256, 0, stream>>>(QKVb, Vt, alpha, Np0, Np1, m1p);
  attn_combine<<<BB * SS, 256, 0, stream>>>(Np0, Np1, m1p, Vsum, factor, attb);

  // proj = att @ Wo + bo  (BF16 out, 128x128 tile)
  gemm128<1, 0, 0><<<cgrid, 256, 0, stream>>>(attb, Wot, bo, projbf, nullptr,
                                              nullptr, EE, EE, (long)SS * EE, 0,
                                              0, (long)SS * EE);
  ln_kernel<<<BB * SS, 256, 0, stream>>>(x, projbf, ln_g, ln_b, out);
}

// Round 25
// 189.967 us; speedup vs baseline: 1.0977x; 1.0047x over previous
//
#include <hip/hip_runtime.h>
#include <math.h>

#define BB 2
#define SS 2048
#define EE 1024
#define HH 16
#define LL 5
#define DH 64
#define QS (3 * 1024)  // QKV fused row stride

typedef __attribute__((ext_vector_type(8))) short bf16x8;
typedef __attribute__((ext_vector_type(4))) float f32x4;

__device__ __forceinline__ unsigned short f2bf(float f) {
  unsigned u = __float_as_uint(f);
  u += 0x7fffu + ((u >> 16) & 1u);
  return (unsigned short)(u >> 16);
}
__device__ __forceinline__ float bf2f(unsigned short u) {
  return __uint_as_float((unsigned)u << 16);
}
__device__ __forceinline__ f32x4 mfma16(bf16x8 a, bf16x8 b, f32x4 c) {
  return __builtin_amdgcn_mfma_f32_16x16x32_bf16(a, b, c, 0, 0, 0);
}
// packed f32x2 -> bf16x2 (RNE), no builtin on gfx950 -> inline asm
__device__ __forceinline__ unsigned cvtpk(float a, float b) {
  unsigned r;
  asm("v_cvt_pk_bf16_f32 %0, %1, %2" : "=v"(r) : "v"(a), "v"(b));
  return r;
}
// gfx950 cross-lane row swaps (VALU, not LDS pipe).
__device__ __forceinline__ void swap32(unsigned& a, unsigned& b) {
  asm volatile("v_permlane32_swap_b32 %0, %1" : "+v"(a), "+v"(b));
}
__device__ __forceinline__ void swap16(unsigned& a, unsigned& b) {
  asm volatile("v_permlane16_swap_b32 %0, %1" : "+v"(a), "+v"(b));
}
// async global->LDS, 16B per lane. lds dest must be wave-uniform base + lane*16.
__device__ __forceinline__ void gload16(const unsigned short* g, unsigned short* l) {
  __builtin_amdgcn_global_load_lds(
      (const __attribute__((address_space(1))) void*)g,
      (__attribute__((address_space(3))) void*)l, 16, 0, 0);
}

// ---------------------------------------------------------------------------
// prep_all: flat-grid merge of all prep stages.
//   bid <  20          : prep_pack (factor, beff, bqkv)
//   20 <= bid < 1556   : wprep (Weff / Wq/Wk/Wv/Wo transpose-convert)
//   1556 <= bid < 3604 : cvt x -> bf16
//   bid >= 3604        : zero cemean+Vsum+qkm (8 blocks x 1024 floats)
// ---------------------------------------------------------------------------
__global__ __launch_bounds__(256) void prep_all(
    const float* __restrict__ x, const float* __restrict__ cons,
    const float* __restrict__ gate, const float* __restrict__ Wc,
    const float* __restrict__ bc,
    const float* __restrict__ bq, const float* __restrict__ bk,
    const float* __restrict__ bv,
    const float* __restrict__ W0, const float* __restrict__ W1,
    const float* __restrict__ W2, const float* __restrict__ W3,
    float* __restrict__ beff, float* __restrict__ bqkv,
    float* __restrict__ factor,
    unsigned short* __restrict__ Weft, unsigned short* __restrict__ Wqkvt,
    unsigned short* __restrict__ Wot, unsigned short* __restrict__ xbf,
    float* __restrict__ zbuf) {
  __shared__ float t[64][69];
  int bid = blockIdx.x;
  int tid = threadIdx.x;

  if (bid < 20) {
    // ---- prep_pack body ----
    int i = bid * 256 + tid;
    if (i == 0) {
      float gw[LL][HH];
      for (int l = 0; l < LL; ++l) {
        float mx = -1e30f;
        for (int h = 0; h < HH; ++h) mx = fmaxf(mx, gate[l * HH + h]);
        float s = 0.f;
        for (int h = 0; h < HH; ++h) { gw[l][h] = expf(gate[l * HH + h] - mx); s += gw[l][h]; }
        for (int h = 0; h < HH; ++h) gw[l][h] /= s;
      }
      for (int b = 0; b < BB; ++b)
        for (int h = 0; h < HH; ++h) {
          float f = 1.f;
          for (int l = 0; l < LL; ++l) f *= 1.f + 0.1f * cons[b * HH + l] * gw[l][h];
          factor[b * HH + h] = f;
        }
    }
    if (i < BB * EE) {
      int b = i >> 10, e = i & 1023;
      float a = 0.f;
      #pragma unroll
      for (int l = 0; l < LL; ++l) a += cons[b * HH + l] * bc[l * EE + e];
      beff[i] = a * (1.f / LL);
    } else {
      int j = i - BB * EE;  // 0..3071
      float v = (j < EE) ? bq[j] : (j < 2 * EE) ? bk[j - EE] : bv[j - 2 * EE];
      bqkv[j] = v;
    }
    return;
  }

  if (bid < 20 + 1536) {
    // ---- wprep body: idx -> (x,y,z) of the original (16,16,6) grid ----
    int idx = bid - 20;
    int gx = idx & 15, gy = (idx >> 4) & 15, z = idx >> 8;
    int o0 = gx * 64, e0 = gy * 64;
    if (z < 2) {
      int b = z;
      float w[LL];
      #pragma unroll
      for (int l = 0; l < LL; ++l) w[l] = cons[b * HH + l] * (1.f / LL);
      #pragma unroll
      for (int i = 0; i < 4; ++i) {
        int id2 = tid + i * 256;
        int r = id2 >> 4, c4 = id2 & 15;
        float4 acc = {0.f, 0.f, 0.f, 0.f};
        #pragma unroll
        for (int l = 0; l < LL; ++l) {
          float4 v = *(const float4*)&Wc[(long)l * EE * EE + (long)(e0 + r) * EE + o0 + c4 * 4];
          acc.x += w[l] * v.x; acc.y += w[l] * v.y; acc.z += w[l] * v.z; acc.w += w[l] * v.w;
        }
        t[r][c4 * 4 + 0] = acc.x; t[r][c4 * 4 + 1] = acc.y;
        t[r][c4 * 4 + 2] = acc.z; t[r][c4 * 4 + 3] = acc.w;
      }
    } else {
      const float* W = (z == 2) ? W0 : (z == 3) ? W1 : (z == 4) ? W2 : W3;
      #pragma unroll
      for (int i = 0; i < 4; ++i) {
        int id2 = tid + i * 256;
        int r = id2 >> 4, c4 = id2 & 15;
        float4 v = *(const float4*)&W[(long)(e0 + r) * EE + o0 + c4 * 4];
        t[r][c4 * 4 + 0] = v.x; t[r][c4 * 4 + 1] = v.y;
        t[r][c4 * 4 + 2] = v.z; t[r][c4 * 4 + 3] = v.w;
      }
    }
    __syncthreads();
    unsigned short* Wt = (z < 2) ? (Weft + (size_t)z * EE * EE)
                       : (z < 5) ? (Wqkvt + (size_t)(z - 2) * EE * EE)
                                 : Wot;
    #pragma unroll
    for (int i = 0; i < 2; ++i) {
      int id2 = tid + i * 256;
      int o = id2 >> 3, ech = id2 & 7;
      unsigned short u[8];
      #pragma unroll
      for (int j = 0; j < 8; ++j) u[j] = f2bf(t[ech * 8 + j][o]);
      unsigned short* dst = Wt + (long)(o0 + o) * EE + e0 + ech * 8;
      *(ushort4*)&dst[0] = *(ushort4*)&u[0];
      *(ushort4*)&dst[4] = *(ushort4*)&u[4];
    }
    return;
  }

  if (bid < 20 + 1536 + 2048) {
    // ---- cvt_bf body ----
    long i = (long)(bid - (20 + 1536)) * 256 + tid;
    float4 a = ((const float4*)x)[i * 2];
    float4 b = ((const float4*)x)[i * 2 + 1];
    ushort4 u0 = make_ushort4(f2bf(a.x), f2bf(a.y), f2bf(a.z), f2bf(a.w));
    ushort4 u1 = make_ushort4(f2bf(b.x), f2bf(b.y), f2bf(b.z), f2bf(b.w));
    ((ushort4*)xbf)[i * 2] = u0;
    ((ushort4*)xbf)[i * 2 + 1] = u1;
    return;
  }

  // ---- zero cemean+Vsum+qkm (8192 floats over 8 blocks) ----
  int i = (bid - (20 + 1536 + 2048)) * 1024 + tid * 4;
  *(float4*)&zbuf[i] = make_float4(0.f, 0.f, 0.f, 0.f);
}

// ---------------------------------------------------------------------------
// bf16 MFMA GEMM, 128x128 tile (m97 structure).
// VSPLIT=1: output columns >= 2048 (V of fused QKV) are written TRANSPOSED to
// Vt[bh][d][s]; their column sums (over s) are atomicAdd'ed into Faux (=Vsum).
// MEANOUT=1: per-column means (over rows) atomicAdd'ed into Maux.  When
// VSPLIT, restricted to nt_<16 (the Q|K columns) -> Maux = qkm directly.
// ---------------------------------------------------------------------------
template <int OUTBF, int VSPLIT, int MEANOUT>
__global__ __launch_bounds__(256) void gemm128(
    const unsigned short* __restrict__ A, const unsigned short* __restrict__ Bt,
    const float* __restrict__ bias, void* __restrict__ C,
    unsigned short* __restrict__ VtOut, float* __restrict__ Faux,
    float* __restrict__ Maux,
    int N, int K, long As_z, long Ws_z, long Bs_z, long Cs_z, long Ms_z) {
  int flat = blockIdx.x + gridDim.x * (blockIdx.y + gridDim.y * blockIdx.z);
  int nwg = gridDim.x * gridDim.y * gridDim.z;
  flat = (flat & 7) * (nwg >> 3) + (flat >> 3);
  int nt_ = flat % gridDim.x;
  int rest = flat / gridDim.x;
  int mt_ = rest % gridDim.y;
  int z = rest / gridDim.y;

  const unsigned short* Ab = A + z * As_z + (long)mt_ * 128 * K;
  const unsigned short* Bb = Bt + z * Ws_z + (long)nt_ * 128 * K;
  const float* bb = bias + z * Bs_z + nt_ * 128;

  __shared__ __align__(16) unsigned short As[2][128 * 64];
  __shared__ __align__(16) unsigned short Bs[2][128 * 64];
  int tid = threadIdx.x;
  int w = tid >> 6, lane = tid & 63, c = lane & 15, g = lane >> 4;
  int wrow = (w >> 1) * 64, wcol = (w & 1) * 64;

  #define STG128(srcp, dstbuf, kt)                                             \
    {                                                                          \
      const unsigned short* s_ = (srcp) + (kt) * 64;                           \
      _Pragma("unroll") for (int j = 0; j < 4; ++j) {                          \
        int idx = tid + j * 256;                                               \
        int row = idx >> 3, ch = idx & 7;                                      \
        gload16(s_ + (long)row * K + ((ch ^ (row & 7)) << 3),                  \
                &dstbuf[(idx & ~63) * 8 + (lane)*8]);                          \
      }                                                                        \
    }

  f32x4 acc[4][4];
  #pragma unroll
  for (int mi = 0; mi < 4; ++mi)
    #pragma unroll
    for (int ni = 0; ni < 4; ++ni) acc[mi][ni] = {0.f, 0.f, 0.f, 0.f};

  int nk = K >> 6;
  STG128(Ab, As[0], 0) STG128(Bb, Bs[0], 0)
  __syncthreads();
  int buf = 0;
  for (int kt = 0; kt < nk; ++kt) {
    if (kt + 1 < nk) { STG128(Ab, As[buf ^ 1], kt + 1) STG128(Bb, Bs[buf ^ 1], kt + 1) }
    #pragma unroll
    for (int kk = 0; kk < 2; ++kk) {
      bf16x8 af[4], bfv[4];
      #pragma unroll
      for (int mi = 0; mi < 4; ++mi) {
        int row = wrow + mi * 16 + c;
        af[mi] = *(const bf16x8*)&As[buf][row * 64 + ((((kk << 2) + g) ^ (row & 7)) << 3)];
      }
      #pragma unroll
      for (int ni = 0; ni < 4; ++ni) {
        int row = wcol + ni * 16 + c;
        bfv[ni] = *(const bf16x8*)&Bs[buf][row * 64 + ((((kk << 2) + g) ^ (row & 7)) << 3)];
      }
      #pragma unroll
      for (int mi = 0; mi < 4; ++mi)
        #pragma unroll
        for (int ni = 0; ni < 4; ++ni)
          acc[mi][ni] = mfma16(af[mi], bfv[ni], acc[mi][ni]);
    }
    __syncthreads();
    buf ^= 1;
  }

  float bval[4];
  #pragma unroll
  for (int ni = 0; ni < 4; ++ni) bval[ni] = bb[wcol + ni * 16 + c];

  if (MEANOUT && (!VSPLIT || nt_ < 16)) {
    // fused column-mean: per-thread 16-row partial, g-shfl reduce, 1 atomic.
    // For VSPLIT (QKV gemm) this computes qkm = mean_s(Q|K) + bias directly.
    #pragma unroll
    for (int ni = 0; ni < 4; ++ni) {
      float colsum = 16.f * bval[ni];
      #pragma unroll
      for (int mi = 0; mi < 4; ++mi)
        colsum += (acc[mi][ni][0] + acc[mi][ni][1]) +
                  (acc[mi][ni][2] + acc[mi][ni][3]);
      colsum += __shfl_xor(colsum, 16);
      colsum += __shfl_xor(colsum, 32);
      if (g == 0) {
        long col = (long)nt_ * 128 + wcol + ni * 16 + c;
        atomicAdd(&Maux[z * Ms_z + col], colsum * (1.f / SS));
      }
    }
  }

  if (VSPLIT && nt_ >= 16) {
    // V columns: write transposed bf16 into Vt[bh][d][s]; fuse Vsum (sum over s)
    #pragma unroll
    for (int mi = 0; mi < 4; ++mi) {
      long s0 = (long)mt_ * 128 + wrow + mi * 16 + g * 4;
      #pragma unroll
      for (int ni = 0; ni < 4; ++ni) {
        int vc = (nt_ - 16) * 128 + wcol + ni * 16 + c;
        int bh = z * HH + (vc >> 6);
        int d = vc & 63;
        float a0 = acc[mi][ni][0] + bval[ni];
        float a1 = acc[mi][ni][1] + bval[ni];
        float a2 = acc[mi][ni][2] + bval[ni];
        float a3 = acc[mi][ni][3] + bval[ni];
        *(uint2*)&VtOut[((long)bh * 64 + d) * SS + s0] =
            make_uint2(cvtpk(a0, a1), cvtpk(a2, a3));
      }
    }
    #pragma unroll
    for (int ni = 0; ni < 4; ++ni) {
      float vsum = 16.f * bval[ni];
      #pragma unroll
      for (int mi = 0; mi < 4; ++mi)
        vsum += (acc[mi][ni][0] + acc[mi][ni][1]) +
                (acc[mi][ni][2] + acc[mi][ni][3]);
      vsum += __shfl_xor(vsum, 16);
      vsum += __shfl_xor(vsum, 32);
      if (g == 0) {
        int vc = (nt_ - 16) * 128 + wcol + ni * 16 + c;
        atomicAdd(&Faux[(z * HH + (vc >> 6)) * 64 + (vc & 63)], vsum);
      }
    }
  } else {
    #pragma unroll
    for (int mi = 0; mi < 4; ++mi)
      #pragma unroll
      for (int ni = 0; ni < 4; ++ni) {
        long col = (long)nt_ * 128 + wcol + ni * 16 + c;
        #pragma unroll
        for (int r = 0; r < 4; ++r) {
          long row = (long)mt_ * 128 + wrow + mi * 16 + g * 4 + r;
          float v = acc[mi][ni][r] + bval[ni];
          if (OUTBF)
            ((unsigned short*)C)[z * Cs_z + row * N + col] = f2bf(v);
          else
            ((float*)C)[z * Cs_z + row * N + col] = v;
        }
      }
  }
  #undef STG128
}

// ---------------------------------------------------------------------------
// cw: alpha[b,h] = 1 + sigmoid(gelu(ci@Wc1+bc1)@Wc2+bc2); ci from qkm.
// ---------------------------------------------------------------------------
__global__ __launch_bounds__(256) void cw_kernel(
    const float* __restrict__ qkm,
    const float* __restrict__ Wc1, const float* __restrict__ bc1,
    const float* __restrict__ Wc2, const float* __restrict__ bc2,
    float* __restrict__ alpha) {
  int bh = blockIdx.x, b = bh / HH, h = bh % HH;
  __shared__ float ci[128];
  __shared__ float pr[4];
  int tid = threadIdx.x;
  if (tid < 128)
    ci[tid] = qkm[b * 2048 + ((tid < 64) ? 0 : 1024) + h * 64 + (tid & 63)];
  __syncthreads();
  float part = 0.f;
  for (int j = tid; j < EE; j += 256) {
    float acc = bc1[j];
    #pragma unroll 8
    for (int i = 0; i < 128; ++i) acc += ci[i] * Wc1[i * EE + j];
    float ge = 0.5f * acc * (1.f + erff(acc * 0.70710678118654752f));
    part += ge * Wc2[j];
  }
  #pragma unroll
  for (int off = 32; off; off >>= 1) part += __shfl_xor(part, off);
  if ((tid & 63) == 0) pr[tid >> 6] = part;
  __syncthreads();
  if (tid == 0) {
    float tot = pr[0] + pr[1] + pr[2] + pr[3] + bc2[0];
    float cw = 1.f / (1.f + expf(-tot));
    alpha[bh] = 1.f + cw;
  }
}

// ---------------------------------------------------------------------------
// Linearized attention (round-17/18 proven config): P in registers via
// permlane swaps; __expf(s*scaleE) (fast v_exp path); LDS 16KB; t-split x2;
// 4 waves x 32 q; T14 reg-staged K/V.
// Partials: m1p[part][b][h][s] f32; Np[part][b][s][e] bf16.
// ---------------------------------------------------------------------------
__global__ __launch_bounds__(256, 4) void attn_lin(
    const unsigned short* __restrict__ QKV,  // [b][s][3072]
    const unsigned short* __restrict__ Vt,   // [bh][d][s]
    const float* __restrict__ alpha,
    unsigned short* __restrict__ Np0, unsigned short* __restrict__ Np1,
    float* __restrict__ m1p) {
  int flat = blockIdx.x;
  flat = (flat & 7) * 128 + (flat >> 3);  // chunked XCD remap, nwg=1024
  int qt = flat & 15, h = (flat >> 4) & 15, b = (flat >> 8) & 1, part = flat >> 9;
  int bh = b * HH + h;
  int tid = threadIdx.x;
  int l = tid & 63, w = tid >> 6, c = l & 15, g = l >> 4;
  __shared__ __align__(16) unsigned short kbuf[4096];      // 8 KB
  __shared__ __align__(16) unsigned short vbuf[4096];      // 8 KB

  const unsigned short* Kb_ =
      QKV + (long)b * SS * QS + EE + h * 64 + (long)part * 1024 * QS;
  const unsigned short* Vb_ = Vt + (long)bh * 64 * SS + part * 1024;
  unsigned short* Np = part ? Np1 : Np0;
  const float scaleE = alpha[bh] * 0.125f;  // (1+cw)/sqrt(64)
  const f32x4 zero4 = {0.f, 0.f, 0.f, 0.f};

  // Q fragments: 2 q-subblocks x 2 k-halves, loaded once from global.
  bf16x8 qf[2][2];
  {
    const unsigned short* qp =
        QKV + ((long)b * SS + qt * 128 + w * 32 + c) * QS + h * 64;
    qf[0][0] = *(const bf16x8*)(qp + 8 * g);
    qf[0][1] = *(const bf16x8*)(qp + 32 + 8 * g);
    qf[1][0] = *(const bf16x8*)(qp + 16 * QS + 8 * g);
    qf[1][1] = *(const bf16x8*)(qp + 16 * QS + 32 + 8 * g);
  }

  // staging addresses: 2 chunks/thread/operand, source chunk-XOR pre-swizzled
  int off1 = tid, off2 = tid + 256;
  int r1 = off1 >> 3, ch1 = ((off1 & 7) ^ (r1 & 7)) << 3;
  int r2 = off2 >> 3, ch2 = ((off2 & 7) ^ (r2 & 7)) << 3;
  const unsigned short* kg1 = Kb_ + (long)r1 * QS + ch1;
  const unsigned short* kg2 = Kb_ + (long)r2 * QS + ch2;
  const unsigned short* vg1 = Vb_ + (long)r1 * SS + ch1;
  const unsigned short* vg2 = Vb_ + (long)r2 * SS + ch2;

  // prologue: tile 0 -> regs -> LDS
  uint4 ks1 = *(const uint4*)kg1, ks2 = *(const uint4*)kg2;
  uint4 vs1 = *(const uint4*)vg1, vs2 = *(const uint4*)vg2;
  kg1 += (long)64 * QS; kg2 += (long)64 * QS; vg1 += 64; vg2 += 64;
  *(uint4*)&kbuf[off1 * 8] = ks1; *(uint4*)&kbuf[off2 * 8] = ks2;
  *(uint4*)&vbuf[off1 * 8] = vs1; *(uint4*)&vbuf[off2 * 8] = vs2;
  __syncthreads();

  f32x4 N1[4][2];
  #pragma unroll
  for (int d = 0; d < 4; ++d) { N1[d][0] = zero4; N1[d][1] = zero4; }
  float m1l0 = 0.f, m1l1 = 0.f;

  const int NT2 = 16;  // 1024 t / 64
  for (int t = 0; t < NT2; ++t) {
    if (t + 1 < NT2) {  // issue next-tile loads early (hide HBM under compute)
      ks1 = *(const uint4*)kg1; ks2 = *(const uint4*)kg2;
      vs1 = *(const uint4*)vg1; vs2 = *(const uint4*)vg2;
      kg1 += (long)64 * QS; kg2 += (long)64 * QS; vg1 += 64; vg2 += 64;
    }
    __builtin_amdgcn_s_setprio(1);
    #pragma unroll
    for (int half = 0; half < 2; ++half) {
      // QK^T for this 32-t half (mt = 2*half+mth); u = exp(scale*s); pack.
      unsigned sA[2][2], sB[2][2];  // [qb][mth]: sA = t{..0,1}, sB = t{..2,3}
      #pragma unroll
      for (int mth = 0; mth < 2; ++mth) {
        int mt = half * 2 + mth;
        int r = mt * 16 + c;
        bf16x8 a0 = *(const bf16x8*)&kbuf[r * 64 + ((g ^ (r & 7)) << 3)];
        bf16x8 a1 = *(const bf16x8*)&kbuf[r * 64 + (((4 + g) ^ (r & 7)) << 3)];
        #pragma unroll
        for (int qb = 0; qb < 2; ++qb) {
          f32x4 s = mfma16(a0, qf[qb][0], zero4);
          s = mfma16(a1, qf[qb][1], s);
          float u0 = __expf(s[0] * scaleE), u1 = __expf(s[1] * scaleE);
          float u2 = __expf(s[2] * scaleE), u3 = __expf(s[3] * scaleE);
          if (qb == 0) m1l0 += (u0 + u1) + (u2 + u3);
          else         m1l1 += (u0 + u1) + (u2 + u3);
          sA[qb][mth] = cvtpk(u0, u1);
          sB[qb][mth] = cvtpk(u2, u3);
        }
      }
      // In-register redistribution to PV B-fragment layout.
      bf16x8 pf[2];
      #pragma unroll
      for (int qb = 0; qb < 2; ++qb) {
        unsigned w0 = sA[qb][0], w2 = sA[qb][1];
        swap32(w0, w2); swap16(w0, w2);
        unsigned w1 = sB[qb][0], w3 = sB[qb][1];
        swap32(w1, w3); swap16(w1, w3);
        union { unsigned u[4]; bf16x8 hv; } pk;
        pk.u[0] = w0; pk.u[1] = w1; pk.u[2] = w2; pk.u[3] = w3;
        pf[qb] = pk.hv;
      }
      // PV for this t-half: N1[d][q] += V[d][t-half] * P[t-half][q]
      #pragma unroll
      for (int dblk = 0; dblk < 4; ++dblk) {
        int r = dblk * 16 + c;
        bf16x8 v = *(const bf16x8*)&vbuf[r * 64 + (((half * 4 + g) ^ (r & 7)) << 3)];
        N1[dblk][0] = mfma16(v, pf[0], N1[dblk][0]);
        N1[dblk][1] = mfma16(v, pf[1], N1[dblk][1]);
      }
    }
    __builtin_amdgcn_s_setprio(0);
    __syncthreads();  // all waves done reading kbuf/vbuf
    if (t + 1 < NT2) {  // write next tile (compiler inserts vmcnt wait)
      *(uint4*)&kbuf[off1 * 8] = ks1; *(uint4*)&kbuf[off2 * 8] = ks2;
      *(uint4*)&vbuf[off1 * 8] = vs1; *(uint4*)&vbuf[off2 * 8] = vs2;
    }
    __syncthreads();  // writes visible before next-tile reads
  }

  // m1 per q-col: reduce across the 4 g-lane-groups
  m1l0 += __shfl_xor(m1l0, 16); m1l0 += __shfl_xor(m1l0, 32);
  m1l1 += __shfl_xor(m1l1, 16); m1l1 += __shfl_xor(m1l1, 32);
  if (l < 16) {
    long mb = ((long)(part * BB + b) * HH + h) * SS + qt * 128 + w * 32;
    m1p[mb + c] = m1l0;
    m1p[mb + 16 + c] = m1l1;
  }

  #pragma unroll
  for (int qb = 0; qb < 2; ++qb) {
    unsigned short* np =
        Np + ((long)b * SS + qt * 128 + w * 32 + qb * 16 + c) * EE + h * 64;
    #pragma unroll
    for (int dblk = 0; dblk < 4; ++dblk) {
      *(uint2*)&np[dblk * 16 + 4 * g] =
          make_uint2(cvtpk(N1[dblk][qb][0], N1[dblk][qb][1]),
                     cvtpk(N1[dblk][qb][2], N1[dblk][qb][3]));
    }
  }
}

// ---------------------------------------------------------------------------
// Combine: att = bf16( (Vsum + f*(N0+N1)/(m1a+m1b)) / (2048+f) ).  Np bf16.
// ---------------------------------------------------------------------------
__global__ __launch_bounds__(256) void attn_combine(
    const unsigned short* __restrict__ Np0, const unsigned short* __restrict__ Np1,
    const float* __restrict__ m1p, const float* __restrict__ Vsum,
    const float* __restrict__ factor, unsigned short* __restrict__ att) {
  int row = blockIdx.x;  // b*SS + s
  int b = row >> 11, s = row & 2047;
  int e0 = threadIdx.x * 4;
  int h = e0 >> 6, d = e0 & 63;
  int bh = b * HH + h;
  float m1 = m1p[((long)b * HH + h) * SS + s] +
             m1p[((long)(BB + b) * HH + h) * SS + s];
  float fac = factor[bh];
  float c1 = fac / m1;
  float invden = 1.f / ((float)SS + fac);
  long base = (long)row * EE + e0;
  ushort4 a0 = *(const ushort4*)&Np0[base];
  ushort4 a1 = *(const ushort4*)&Np1[base];
  float4 vs = *(const float4*)&Vsum[bh * 64 + d];
  float n0 = bf2f(a0.x) + bf2f(a1.x);
  float n1 = bf2f(a0.y) + bf2f(a1.y);
  float n2 = bf2f(a0.z) + bf2f(a1.z);
  float n3 = bf2f(a0.w) + bf2f(a1.w);
  float o0 = (vs.x + c1 * n0) * invden;
  float o1 = (vs.y + c1 * n1) * invden;
  float o2 = (vs.z + c1 * n2) * invden;
  float o3 = (vs.w + c1 * n3) * invden;
  *(uint2*)&att[base] = make_uint2(cvtpk(o0, o1), cvtpk(o2, o3));
}

// ---------------------------------------------------------------------------
// LayerNorm(x + proj) * g + b.  proj bf16; thread owns 4 contiguous elems.
// ---------------------------------------------------------------------------
__global__ __launch_bounds__(256) void ln_kernel(
    const float* __restrict__ x, const unsigned short* __restrict__ proj,
    const float* __restrict__ g, const float* __restrict__ bb,
    float* __restrict__ out) {
  long row = blockIdx.x;
  const float* xp = x + row * EE;
  const unsigned short* pp = proj + row * EE;
  int tid = threadIdx.x;
  int e0 = tid * 4;
  float v[4];
  __shared__ float r1[4], r2[4];
  float4 xv = *(const float4*)&xp[e0];
  ushort4 pv = *(const ushort4*)&pp[e0];
  v[0] = xv.x + bf2f(pv.x);
  v[1] = xv.y + bf2f(pv.y);
  v[2] = xv.z + bf2f(pv.z);
  v[3] = xv.w + bf2f(pv.w);
  float s = (v[0] + v[1]) + (v[2] + v[3]);
  #pragma unroll
  for (int off = 32; off; off >>= 1) s += __shfl_xor(s, off);
  if ((tid & 63) == 0) r1[tid >> 6] = s;
  __syncthreads();
  float mean = (r1[0] + r1[1] + r1[2] + r1[3]) * (1.f / EE);
  float s2 = 0.f;
  #pragma unroll
  for (int i = 0; i < 4; ++i) { float d = v[i] - mean; s2 += d * d; }
  #pragma unroll
  for (int off = 32; off; off >>= 1) s2 += __shfl_xor(s2, off);
  if ((tid & 63) == 0) r2[tid >> 6] = s2;
  __syncthreads();
  float rstd = rsqrtf((r2[0] + r2[1] + r2[2] + r2[3]) * (1.f / EE) + 1e-5f);
  float4 gv = *(const float4*)&g[e0];
  float4 bv = *(const float4*)&bb[e0];
  float4 o;
  o.x = (v[0] - mean) * rstd * gv.x + bv.x;
  o.y = (v[1] - mean) * rstd * gv.y + bv.y;
  o.z = (v[2] - mean) * rstd * gv.z + bv.z;
  o.w = (v[3] - mean) * rstd * gv.w + bv.w;
  *(float4*)&out[row * EE + e0] = o;
}

// ---------------------------------------------------------------------------
extern "C" void kernel_launch(void* const* d_in, const int* in_sizes, int n_in,
                              void* d_out, int out_size, void* d_ws, size_t ws_size,
                              hipStream_t stream) {
  (void)in_sizes; (void)n_in; (void)out_size; (void)ws_size;
  const float* x    = (const float*)d_in[0];
  const float* cons = (const float*)d_in[1];
  const float* Wc   = (const float*)d_in[2];
  const float* bc   = (const float*)d_in[3];
  // d_in[4] Wf, d_in[5] bf, d_in[19] phi_phase: unused (phase term cancels)
  const float* Wq   = (const float*)d_in[6];
  const float* bq   = (const float*)d_in[7];
  const float* Wk   = (const float*)d_in[8];
  const float* bk   = (const float*)d_in[9];
  const float* Wv   = (const float*)d_in[10];
  const float* bv   = (const float*)d_in[11];
  const float* Wo   = (const float*)d_in[12];
  const float* bo   = (const float*)d_in[13];
  const float* Wc1  = (const float*)d_in[14];
  const float* bc1  = (const float*)d_in[15];
  const float* Wc2  = (const float*)d_in[16];
  const float* bc2  = (const float*)d_in[17];
  const float* gate = (const float*)d_in[18];
  const float* ln_g = (const float*)d_in[20];
  const float* ln_b = (const float*)d_in[21];
  float* out = (float*)d_out;

  const size_t MSZ = (size_t)BB * SS * EE;  // 4M elems
  float* p = (float*)d_ws;
  float* beff = p;  p += BB * EE;
  float* factor = p; p += 32;
  float* alpha  = p; p += 32;
  float* cemean = p; p += BB * EE;  // cemean+Vsum+qkm contiguous: zeroed in prep_all
  float* Vsum = p;  p += BB * EE;
  float* qkm  = p;  p += BB * 2 * EE;
  float* bqkv = p;  p += QS;
  unsigned short* projbf = (unsigned short*)p;  p += MSZ / 2;  // bf16 proj
  unsigned short* q = (unsigned short*)p;
  unsigned short* xbf  = q;  q += MSZ;
  unsigned short* cebf = q;  q += MSZ;
  unsigned short* QKVb = q;  q += 3 * MSZ;  // V third never written (diverted)
  unsigned short* Vt   = q;  q += MSZ;
  unsigned short* attb = q;  q += MSZ;
  unsigned short* Weft = q;  q += (size_t)BB * EE * EE;
  unsigned short* Wqkvt= q;  q += (size_t)3 * EE * EE;
  unsigned short* Wot  = q;  q += (size_t)EE * EE;
  float* m1p = (float*)q;    q += 2 * 2 * BB * HH * SS;  // [2][b][h][s] f32
  // bf16 N partials alias dead regions:
  unsigned short* Np0 = xbf;   // dead after ce gemm
  unsigned short* Np1 = cebf;  // dead after QKV gemm

  // merged prep: prep_pack (20) + wprep (1536) + cvt x->bf16 (2048)
  //            + zero cemean/Vsum/qkm (8) blocks
  prep_all<<<20 + 1536 + 2048 + 8, 256, 0, stream>>>(
      x, cons, gate, Wc, bc, bq, bk, bv, Wq, Wk, Wv, Wo,
      beff, bqkv, factor, Weft, Wqkvt, Wot, xbf, cemean);

  // ce = x @ Weff + beff  (bf16 out, 128x128 tile) + fused column-mean
  dim3 cgrid(EE / 128, SS / 128, BB);  // 8x16x2 = 256 wgs
  gemm128<1, 0, 1><<<cgrid, 256, 0, stream>>>(
      xbf, Weft, beff, cebf, nullptr, nullptr, cemean, EE, EE, (long)SS * EE,
      (long)EE * EE, EE, (long)SS * EE, EE);

  // QKV = ce @ [Wq|Wk|Wv] + [bq|bk|bv]; V diverted to Vt transposed + fused
  // Vsum; Q|K column-means atomicAdd'ed into qkm (replaces qkmean kernel).
  dim3 qgrid(QS / 128, SS / 128, BB);  // 24x16x2 = 768 wgs
  gemm128<1, 1, 1><<<qgrid, 256, 0, stream>>>(
      cebf, Wqkvt, bqkv, QKVb, Vt, Vsum, qkm, QS, EE, (long)SS * EE, 0, 0,
      (long)SS * QS, 2 * EE);

  // alpha from qkm (qkm complete after QKV gemm)
  cw_kernel<<<BB * HH, 256, 0, stream>>>(qkm, Wc1, bc1, Wc2, bc2, alpha);

  attn_lin<<<1024, 256, 0, stream>>>(QKVb, Vt, alpha, Np0, Np1, m1p);
  attn_combine<<<BB * SS, 256, 0, stream>>>(Np0, Np1, m1p, Vsum, factor, attb);

  // proj = att @ Wo + bo  (BF16 out, 128x128 tile)
  gemm128<1, 0, 0><<<cgrid, 256, 0, stream>>>(
      attb, Wot, bo, projbf, nullptr, nullptr, nullptr, EE, EE, (long)SS * EE,
      0, 0, (long)SS * EE, 0);
  ln_kernel<<<BB * SS, 256, 0, stream>>>(x, projbf, ln_g, ln_b, out);
}